// Round 1
// baseline (4003.448 us; speedup 1.0000x reference)
//
#include <hip/hip_runtime.h>
#include <math.h>

#define NNODE 100000
#define NEDGE 600000
#define DIM 128
#define HID 256
#define NLAYERS 2
#define TE 32
#define TN 16

__device__ __forceinline__ float gelu_exact(float x) {
    return 0.5f * x * (1.0f + erff(x * 0.70710678118654752f));
}
__device__ __forceinline__ float sigmoidf_(float x) {
    return 1.0f / (1.0f + expf(-x));
}
__device__ __forceinline__ float wave_reduce_sum(float v) {
#pragma unroll
    for (int off = 32; off > 0; off >>= 1) v += __shfl_xor(v, off);
    return v;
}

// ---------------- Edge kernel ----------------
// block: 256 threads, TE=32 edges. Computes gate per edge, scatters msg & den.
__global__ __launch_bounds__(256, 2)
void edge_kernel(const float* __restrict__ h,
                 const int* __restrict__ ei,      // [E][2] (src, dst)
                 const float* __restrict__ attr,  // [E]
                 const float* __restrict__ W1,    // [257][256]
                 const float* __restrict__ b1,    // [256]
                 const float* __restrict__ W2,    // [256]
                 const float* __restrict__ b2,    // [1]
                 float* __restrict__ agg,         // [N][128]
                 float* __restrict__ den)         // [N]
{
    __shared__ float X[TE][260];      // [edge][0..127 src | 128..255 dst | 256 attr]
    __shared__ float Wt[32][256];
    __shared__ float gate_s[TE];

    const int tid = threadIdx.x;
    const int e0 = blockIdx.x * TE;

    // ---- gather X ----
    for (int idx = tid; idx < TE * 64; idx += 256) {
        int e = idx >> 6, q = idx & 63;
        long ge = e0 + e;
        int node = (q < 32) ? ei[2 * ge] : ei[2 * ge + 1];
        float4 v = ((const float4*)(h + (long)node * DIM))[q & 31];
        *((float4*)&X[e][(q & 31) * 4 + ((q < 32) ? 0 : 128)]) = v;
    }
    if (tid < TE) X[tid][256] = attr[e0 + tid];
    __syncthreads();

    const int jg = tid & 63;   // column group: j0 = jg*4
    const int eg = tid >> 6;   // wave id; edges eg + 4*i
    const int j0 = jg * 4;

    float acc[8][4];
#pragma unroll
    for (int i = 0; i < 8; ++i)
#pragma unroll
        for (int m = 0; m < 4; ++m) acc[i][m] = 0.f;

    for (int kt = 0; kt < 256; kt += 32) {
        // stage W1 k-tile
        for (int idx = tid; idx < 32 * 64; idx += 256) {
            int kr = idx >> 6, jq = idx & 63;
            *((float4*)&Wt[kr][jq * 4]) = ((const float4*)(W1 + (long)(kt + kr) * 256))[jq];
        }
        __syncthreads();
#pragma unroll
        for (int k = 0; k < 32; k += 4) {
            const float4 w0 = *((const float4*)&Wt[k + 0][j0]);
            const float4 w1 = *((const float4*)&Wt[k + 1][j0]);
            const float4 w2 = *((const float4*)&Wt[k + 2][j0]);
            const float4 w3 = *((const float4*)&Wt[k + 3][j0]);
#pragma unroll
            for (int i = 0; i < 8; ++i) {
                const float4 x = *((const float4*)&X[eg + 4 * i][kt + k]);
                acc[i][0] = fmaf(x.x, w0.x, fmaf(x.y, w1.x, fmaf(x.z, w2.x, fmaf(x.w, w3.x, acc[i][0]))));
                acc[i][1] = fmaf(x.x, w0.y, fmaf(x.y, w1.y, fmaf(x.z, w2.y, fmaf(x.w, w3.y, acc[i][1]))));
                acc[i][2] = fmaf(x.x, w0.z, fmaf(x.y, w1.z, fmaf(x.z, w2.z, fmaf(x.w, w3.z, acc[i][2]))));
                acc[i][3] = fmaf(x.x, w0.w, fmaf(x.y, w1.w, fmaf(x.z, w2.w, fmaf(x.w, w3.w, acc[i][3]))));
            }
        }
        __syncthreads();
    }

    // attr row (k = 256), bias, gelu, dot with W2, sigmoid
    const float4 wa  = ((const float4*)(W1 + 256L * 256))[jg];
    const float4 b1v = ((const float4*)b1)[jg];
    const float4 w2c = ((const float4*)W2)[jg];
    const float b2v = b2[0];

#pragma unroll
    for (int i = 0; i < 8; ++i) {
        const int e = eg + 4 * i;
        const float a = X[e][256];
        float p0 = gelu_exact(fmaf(a, wa.x, acc[i][0] + b1v.x));
        float p1 = gelu_exact(fmaf(a, wa.y, acc[i][1] + b1v.y));
        float p2 = gelu_exact(fmaf(a, wa.z, acc[i][2] + b1v.z));
        float p3 = gelu_exact(fmaf(a, wa.w, acc[i][3] + b1v.w));
        float partial = p0 * w2c.x + p1 * w2c.y + p2 * w2c.z + p3 * w2c.w;
        partial = wave_reduce_sum(partial);
        if ((tid & 63) == 0) {
            float gate = sigmoidf_(partial + b2v);
            gate_s[e] = gate;
            atomicAdd(&den[ei[2L * (e0 + e) + 1]], gate);
        }
    }
    __syncthreads();

    // scatter msg = h_src * gate
    for (int idx = tid; idx < TE * 32; idx += 256) {
        int e = idx >> 5, q = idx & 31;
        float g = gate_s[e];
        int d = ei[2L * (e0 + e) + 1];
        float4 hs = *((const float4*)&X[e][q * 4]);
        float* ap = agg + (long)d * DIM + q * 4;
        atomicAdd(ap + 0, hs.x * g);
        atomicAdd(ap + 1, hs.y * g);
        atomicAdd(ap + 2, hs.z * g);
        atomicAdd(ap + 3, hs.w * g);
    }
}

// ---------------- Node kernel ----------------
// block: 256 threads, TN=16 nodes. u=[h, agg/den] -> gelu(u W1 + b1) W2 + b2; LN(h+upd).
__global__ __launch_bounds__(256, 2)
void node_kernel(const float* __restrict__ h,
                 const float* __restrict__ agg,
                 const float* __restrict__ den,
                 const float* __restrict__ W1,   // [256][256]
                 const float* __restrict__ b1,   // [256]
                 const float* __restrict__ W2,   // [256][128]
                 const float* __restrict__ b2,   // [128]
                 const float* __restrict__ lng,  // [128]
                 const float* __restrict__ lnb,  // [128]
                 float* __restrict__ hout)       // [N][128]
{
    __shared__ float U[TN][260];   // [node][0..127 h | 128..255 agg/den]
    __shared__ float G[TN][260];   // gelu output, later reused for h+upd
    __shared__ float Wt[32][256];

    const int tid = threadIdx.x;
    const int n0 = blockIdx.x * TN;

    // ---- stage U ----
    for (int idx = tid; idx < TN * 64; idx += 256) {
        int n = idx >> 6, q = idx & 63;
        long gn = n0 + n;
        float4 v;
        if (q < 32) {
            v = ((const float4*)(h + gn * DIM))[q];
        } else {
            v = ((const float4*)(agg + gn * DIM))[q - 32];
            float inv = 1.0f / fmaxf(den[gn], 1e-6f);
            v.x *= inv; v.y *= inv; v.z *= inv; v.w *= inv;
        }
        *((float4*)&U[n][q * 4]) = v;
    }
    __syncthreads();

    // ---- GEMM1: [16][256] x [256][256] ----
    const int jg = tid & 63;    // j0 = jg*4
    const int ng = tid >> 6;    // nodes ng + 4*i
    const int j0 = jg * 4;

    float acc1[4][4];
#pragma unroll
    for (int i = 0; i < 4; ++i)
#pragma unroll
        for (int m = 0; m < 4; ++m) acc1[i][m] = 0.f;

    for (int kt = 0; kt < 256; kt += 32) {
        for (int idx = tid; idx < 32 * 64; idx += 256) {
            int kr = idx >> 6, jq = idx & 63;
            *((float4*)&Wt[kr][jq * 4]) = ((const float4*)(W1 + (long)(kt + kr) * 256))[jq];
        }
        __syncthreads();
#pragma unroll
        for (int k = 0; k < 32; k += 4) {
            const float4 w0 = *((const float4*)&Wt[k + 0][j0]);
            const float4 w1 = *((const float4*)&Wt[k + 1][j0]);
            const float4 w2 = *((const float4*)&Wt[k + 2][j0]);
            const float4 w3 = *((const float4*)&Wt[k + 3][j0]);
#pragma unroll
            for (int i = 0; i < 4; ++i) {
                const float4 x = *((const float4*)&U[ng + 4 * i][kt + k]);
                acc1[i][0] = fmaf(x.x, w0.x, fmaf(x.y, w1.x, fmaf(x.z, w2.x, fmaf(x.w, w3.x, acc1[i][0]))));
                acc1[i][1] = fmaf(x.x, w0.y, fmaf(x.y, w1.y, fmaf(x.z, w2.y, fmaf(x.w, w3.y, acc1[i][1]))));
                acc1[i][2] = fmaf(x.x, w0.z, fmaf(x.y, w1.z, fmaf(x.z, w2.z, fmaf(x.w, w3.z, acc1[i][2]))));
                acc1[i][3] = fmaf(x.x, w0.w, fmaf(x.y, w1.w, fmaf(x.z, w2.w, fmaf(x.w, w3.w, acc1[i][3]))));
            }
        }
        __syncthreads();
    }

    const float4 b1v = ((const float4*)b1)[jg];
#pragma unroll
    for (int i = 0; i < 4; ++i) {
        int n = ng + 4 * i;
        G[n][j0 + 0] = gelu_exact(acc1[i][0] + b1v.x);
        G[n][j0 + 1] = gelu_exact(acc1[i][1] + b1v.y);
        G[n][j0 + 2] = gelu_exact(acc1[i][2] + b1v.z);
        G[n][j0 + 3] = gelu_exact(acc1[i][3] + b1v.w);
    }
    __syncthreads();

    // ---- GEMM2: [16][256] x [256][128] ----
    const int jg2 = tid & 31;   // j0b = jg2*4  (output dim 128)
    const int ng2 = tid >> 5;   // nodes ng2 + 8*i
    const int j0b = jg2 * 4;

    float acc2[2][4];
#pragma unroll
    for (int i = 0; i < 2; ++i)
#pragma unroll
        for (int m = 0; m < 4; ++m) acc2[i][m] = 0.f;

    for (int kt = 0; kt < 256; kt += 32) {
        for (int idx = tid; idx < 32 * 32; idx += 256) {
            int kr = idx >> 5, jq = idx & 31;
            *((float4*)&Wt[kr][jq * 4]) = ((const float4*)(W2 + (long)(kt + kr) * 128))[jq];
        }
        __syncthreads();
#pragma unroll
        for (int k = 0; k < 32; k += 4) {
            const float4 w0 = *((const float4*)&Wt[k + 0][j0b]);
            const float4 w1 = *((const float4*)&Wt[k + 1][j0b]);
            const float4 w2 = *((const float4*)&Wt[k + 2][j0b]);
            const float4 w3 = *((const float4*)&Wt[k + 3][j0b]);
#pragma unroll
            for (int i = 0; i < 2; ++i) {
                const float4 x = *((const float4*)&G[ng2 + 8 * i][kt + k]);
                acc2[i][0] = fmaf(x.x, w0.x, fmaf(x.y, w1.x, fmaf(x.z, w2.x, fmaf(x.w, w3.x, acc2[i][0]))));
                acc2[i][1] = fmaf(x.x, w0.y, fmaf(x.y, w1.y, fmaf(x.z, w2.y, fmaf(x.w, w3.y, acc2[i][1]))));
                acc2[i][2] = fmaf(x.x, w0.z, fmaf(x.y, w1.z, fmaf(x.z, w2.z, fmaf(x.w, w3.z, acc2[i][2]))));
                acc2[i][3] = fmaf(x.x, w0.w, fmaf(x.y, w1.w, fmaf(x.z, w2.w, fmaf(x.w, w3.w, acc2[i][3]))));
            }
        }
        __syncthreads();
    }

    // upd + bias + residual -> write into G[:, 0..127] (disjoint from last-tile reads at cols 224..255)
    const float4 b2v = ((const float4*)b2)[jg2];
#pragma unroll
    for (int i = 0; i < 2; ++i) {
        int n = ng2 + 8 * i;
        G[n][j0b + 0] = acc2[i][0] + b2v.x + U[n][j0b + 0];
        G[n][j0b + 1] = acc2[i][1] + b2v.y + U[n][j0b + 1];
        G[n][j0b + 2] = acc2[i][2] + b2v.z + U[n][j0b + 2];
        G[n][j0b + 3] = acc2[i][3] + b2v.w + U[n][j0b + 3];
    }
    __syncthreads();

    // ---- LayerNorm: wave per node ----
    const int wv = tid >> 6, lane = tid & 63;
#pragma unroll
    for (int ii = 0; ii < TN / 4; ++ii) {
        int n = wv * 4 + ii;
        float2 v = *((const float2*)&G[n][lane * 2]);
        float s = wave_reduce_sum(v.x + v.y);
        float mu = s * (1.0f / 128.0f);
        float dx = v.x - mu, dy = v.y - mu;
        float q = wave_reduce_sum(dx * dx + dy * dy);
        float inv = rsqrtf(q * (1.0f / 128.0f) + 1e-5f);
        float2 gg = *((const float2*)&lng[lane * 2]);
        float2 bb = *((const float2*)&lnb[lane * 2]);
        long gn = n0 + n;
        float2 o;
        o.x = dx * inv * gg.x + bb.x;
        o.y = dy * inv * gg.y + bb.y;
        *((float2*)&hout[gn * DIM + lane * 2]) = o;
    }
}

extern "C" void kernel_launch(void* const* d_in, const int* in_sizes, int n_in,
                              void* d_out, int out_size, void* d_ws, size_t ws_size,
                              hipStream_t stream) {
    const float* h0   = (const float*)d_in[0];
    const int*   ei   = (const int*)d_in[1];
    const float* attr = (const float*)d_in[2];
    const float* ew1  = (const float*)d_in[3];
    const float* eb1  = (const float*)d_in[4];
    const float* ew2  = (const float*)d_in[5];
    const float* eb2  = (const float*)d_in[6];
    const float* nw1  = (const float*)d_in[7];
    const float* nb1  = (const float*)d_in[8];
    const float* nw2  = (const float*)d_in[9];
    const float* nb2  = (const float*)d_in[10];
    const float* lng  = (const float*)d_in[11];
    const float* lnb  = (const float*)d_in[12];

    float* hout = (float*)d_out;
    float* agg  = (float*)d_ws;                       // N*128 floats
    float* den  = agg + (size_t)NNODE * DIM;          // N floats

    for (int L = 0; L < NLAYERS; ++L) {
        hipMemsetAsync(agg, 0, ((size_t)NNODE * DIM + NNODE) * sizeof(float), stream);
        const float* hin = (L == 0) ? h0 : hout;
        edge_kernel<<<NEDGE / TE, 256, 0, stream>>>(
            hin, ei, attr,
            ew1 + (size_t)L * 257 * 256, eb1 + (size_t)L * 256,
            ew2 + (size_t)L * 256, eb2 + L,
            agg, den);
        node_kernel<<<NNODE / TN, 256, 0, stream>>>(
            hin, agg, den,
            nw1 + (size_t)L * 256 * 256, nb1 + (size_t)L * 256,
            nw2 + (size_t)L * 256 * 128, nb2 + (size_t)L * 128,
            lng + (size_t)L * 128, lnb + (size_t)L * 128,
            hout);
    }
}

// Round 2
// 2440.704 us; speedup vs baseline: 1.6403x; 1.6403x over previous
//
#include <hip/hip_runtime.h>
#include <math.h>

#define NNODE 100000
#define NEDGE 600000
#define DIM 128
#define HID 256
#define NLAYERS 2

typedef short bf16x8 __attribute__((ext_vector_type(8)));
typedef short bf16x4 __attribute__((ext_vector_type(4)));
typedef float f32x4 __attribute__((ext_vector_type(4)));

#define WLD 264  // leading dim (bf16 elems) for transposed weights & LDS tiles

__device__ __forceinline__ short f2bf(float x) {
    union { float f; unsigned u; } v; v.f = x;
    unsigned r = v.u + 0x7FFFu + ((v.u >> 16) & 1u);
    return (short)(r >> 16);
}
__device__ __forceinline__ float bf2f(short s) {
    union { unsigned u; float f; } v; v.u = ((unsigned)(unsigned short)s) << 16;
    return v.f;
}
__device__ __forceinline__ float gelu_exact(float x) {
    return 0.5f * x * (1.0f + erff(x * 0.70710678118654752f));
}

// ---------------- prep: transpose + convert weights to bf16 [n][k] ----------------
__global__ void prep_weights(const float* __restrict__ ew1,   // [L][257][256]
                             const float* __restrict__ nw1,   // [L][256][256]
                             const float* __restrict__ nw2,   // [L][256][128]
                             short* __restrict__ eW1T,        // [L][256][WLD]
                             short* __restrict__ nW1T,        // [L][256][WLD]
                             short* __restrict__ nW2T)        // [L][128][WLD]
{
    int idx = blockIdx.x * 256 + threadIdx.x;
    const int SZ1 = NLAYERS * 256 * 256;   // 131072
    const int SZ2 = NLAYERS * 256 * 256;   // 131072
    const int SZ3 = NLAYERS * 128 * 256;   // 65536
    if (idx < SZ1) {
        int L = idx >> 16, r = idx & 65535, n = r >> 8, k = r & 255;
        eW1T[(size_t)L * 256 * WLD + n * WLD + k] = f2bf(ew1[(size_t)L * 257 * 256 + k * 256 + n]);
        return;
    }
    idx -= SZ1;
    if (idx < SZ2) {
        int L = idx >> 16, r = idx & 65535, n = r >> 8, k = r & 255;
        nW1T[(size_t)L * 256 * WLD + n * WLD + k] = f2bf(nw1[(size_t)L * 256 * 256 + k * 256 + n]);
        return;
    }
    idx -= SZ2;
    if (idx < SZ3) {
        int L = idx >> 15, r = idx & 32767, n = r >> 8, k = r & 255;
        nW2T[(size_t)L * 128 * WLD + n * WLD + k] = f2bf(nw2[(size_t)L * 256 * 128 + k * 128 + n]);
    }
}

// ---------------- Edge kernel: 64 edges/block, 4 waves, MFMA bf16 ----------------
__global__ __launch_bounds__(256, 3)
void edge_kernel(const float* __restrict__ h,
                 const int* __restrict__ ei,
                 const float* __restrict__ attr,
                 const short* __restrict__ W1T,   // [256][WLD] bf16 (k=0..255)
                 const float* __restrict__ W1a,   // row k=256 of ew1 (attr weights), [256] f32
                 const float* __restrict__ b1,    // [256]
                 const float* __restrict__ W2,    // [256]
                 const float* __restrict__ b2,    // [1]
                 float* __restrict__ agg,
                 float* __restrict__ den)
{
    __shared__ short Xb[64][WLD];     // bf16: [edge][0..127 src | 128..255 dst]
    __shared__ float glog[64];
    __shared__ float attr_s[64];
    __shared__ int   dst_s[64];

    const int tid = threadIdx.x;
    const int e0 = blockIdx.x * 64;

    if (tid < 64) {
        glog[tid] = 0.f;
        attr_s[tid] = attr[e0 + tid];
        dst_s[tid] = ei[2 * (e0 + tid) + 1];
    }

    // gather X as bf16
    for (int idx = tid; idx < 64 * 32; idx += 256) {
        int e = idx >> 5, q = idx & 31;
        int node = ei[2 * (e0 + e) + (q >= 16 ? 1 : 0)];
        const float4* srcp = (const float4*)(h + (size_t)node * DIM + (q & 15) * 8);
        float4 v0 = srcp[0], v1 = srcp[1];
        bf16x8 t;
        t[0] = f2bf(v0.x); t[1] = f2bf(v0.y); t[2] = f2bf(v0.z); t[3] = f2bf(v0.w);
        t[4] = f2bf(v1.x); t[5] = f2bf(v1.y); t[6] = f2bf(v1.z); t[7] = f2bf(v1.w);
        *(bf16x8*)&Xb[e][q * 8] = t;
    }
    __syncthreads();

    const int lane = tid & 63;
    const int wv = tid >> 6;
    const int n0 = wv * 64;
    const int lrow = lane & 15;
    const int lkg = lane >> 4;

    f32x4 acc[4][4];
#pragma unroll
    for (int mi = 0; mi < 4; ++mi)
#pragma unroll
        for (int ni = 0; ni < 4; ++ni) acc[mi][ni] = (f32x4){0.f, 0.f, 0.f, 0.f};

    const short* xbase = &Xb[lrow][lkg * 8];
    const short* wbase = W1T + (size_t)(n0 + lrow) * WLD + lkg * 8;

#pragma unroll
    for (int kt = 0; kt < 8; ++kt) {
        bf16x8 a[4], b[4];
#pragma unroll
        for (int mi = 0; mi < 4; ++mi)
            a[mi] = *(const bf16x8*)(xbase + mi * 16 * WLD + kt * 32);
#pragma unroll
        for (int ni = 0; ni < 4; ++ni)
            b[ni] = *(const bf16x8*)(wbase + ni * 16 * WLD + kt * 32);
#pragma unroll
        for (int mi = 0; mi < 4; ++mi)
#pragma unroll
            for (int ni = 0; ni < 4; ++ni)
                acc[mi][ni] = __builtin_amdgcn_mfma_f32_16x16x32_bf16(a[mi], b[ni], acc[mi][ni], 0, 0, 0);
    }

    // epilogue: bias + attr rank-1 + gelu + dot W2, subgroup reduce, LDS combine
    float b1v[4], w1av[4], w2v[4];
#pragma unroll
    for (int ni = 0; ni < 4; ++ni) {
        int col = n0 + ni * 16 + lrow;
        b1v[ni] = b1[col]; w1av[ni] = W1a[col]; w2v[ni] = W2[col];
    }
#pragma unroll
    for (int mi = 0; mi < 4; ++mi) {
#pragma unroll
        for (int reg = 0; reg < 4; ++reg) {
            int e = mi * 16 + lkg * 4 + reg;
            float ae = attr_s[e];
            float partial = 0.f;
#pragma unroll
            for (int ni = 0; ni < 4; ++ni) {
                float p = gelu_exact(acc[mi][ni][reg] + b1v[ni] + ae * w1av[ni]);
                partial = fmaf(p, w2v[ni], partial);
            }
            partial += __shfl_xor(partial, 1);
            partial += __shfl_xor(partial, 2);
            partial += __shfl_xor(partial, 4);
            partial += __shfl_xor(partial, 8);
            if (lrow == 0) atomicAdd(&glog[e], partial);
        }
    }
    __syncthreads();

    if (tid < 64) {
        float g = 1.f / (1.f + expf(-(glog[tid] + b2[0])));
        glog[tid] = g;
        atomicAdd(&den[dst_s[tid]], g);
    }
    __syncthreads();

    // scatter msg = gate * h_src
    for (int idx = tid; idx < 64 * 32; idx += 256) {
        int e = idx >> 5, q = idx & 31;
        float g = glog[e];
        int d = dst_s[e];
        bf16x4 hs = *(const bf16x4*)&Xb[e][q * 4];
        float* ap = agg + (size_t)d * DIM + q * 4;
        atomicAdd(ap + 0, bf2f(hs[0]) * g);
        atomicAdd(ap + 1, bf2f(hs[1]) * g);
        atomicAdd(ap + 2, bf2f(hs[2]) * g);
        atomicAdd(ap + 3, bf2f(hs[3]) * g);
    }
}

// ---------------- Node kernel: 64 nodes/block, 4 waves, fused MLP + LN ----------------
__global__ __launch_bounds__(256, 3)
void node_kernel(const float* __restrict__ h,
                 const float* __restrict__ agg,
                 const float* __restrict__ den,
                 const short* __restrict__ W1T,  // [256][WLD]
                 const float* __restrict__ b1,   // [256]
                 const short* __restrict__ W2T,  // [128][WLD]
                 const float* __restrict__ b2,   // [128]
                 const float* __restrict__ lng,
                 const float* __restrict__ lnb,
                 float* __restrict__ hout)
{
    __shared__ short U[64][WLD];   // bf16 [node][h | agg/den]; overlaid later by R f32 [64][132]
    __shared__ short G[64][WLD];   // bf16 gelu output
    __shared__ float dinv[64];

    const int tid = threadIdx.x;
    const int n0 = blockIdx.x * 64;

    if (tid < 64) {
        int gn = min(n0 + tid, NNODE - 1);
        dinv[tid] = 1.f / fmaxf(den[gn], 1e-6f);
    }
    __syncthreads();

    for (int idx = tid; idx < 64 * 32; idx += 256) {
        int nl = idx >> 5, q = idx & 31;
        int gn = min(n0 + nl, NNODE - 1);
        const float4* srcp;
        float sc = 1.f;
        if (q < 16) {
            srcp = (const float4*)(h + (size_t)gn * DIM + q * 8);
        } else {
            srcp = (const float4*)(agg + (size_t)gn * DIM + (q & 15) * 8);
            sc = dinv[nl];
        }
        float4 v0 = srcp[0], v1 = srcp[1];
        bf16x8 t;
        t[0] = f2bf(v0.x * sc); t[1] = f2bf(v0.y * sc); t[2] = f2bf(v0.z * sc); t[3] = f2bf(v0.w * sc);
        t[4] = f2bf(v1.x * sc); t[5] = f2bf(v1.y * sc); t[6] = f2bf(v1.z * sc); t[7] = f2bf(v1.w * sc);
        *(bf16x8*)&U[nl][q * 8] = t;
    }
    __syncthreads();

    const int lane = tid & 63;
    const int wv = tid >> 6;
    const int lrow = lane & 15;
    const int lkg = lane >> 4;

    // ---- GEMM1: [64][256] x [256][256] ----
    {
        const int n0w = wv * 64;
        f32x4 acc1[4][4];
#pragma unroll
        for (int mi = 0; mi < 4; ++mi)
#pragma unroll
            for (int ni = 0; ni < 4; ++ni) acc1[mi][ni] = (f32x4){0.f, 0.f, 0.f, 0.f};

        const short* xbase = &U[lrow][lkg * 8];
        const short* wbase = W1T + (size_t)(n0w + lrow) * WLD + lkg * 8;
#pragma unroll
        for (int kt = 0; kt < 8; ++kt) {
            bf16x8 a[4], b[4];
#pragma unroll
            for (int mi = 0; mi < 4; ++mi)
                a[mi] = *(const bf16x8*)(xbase + mi * 16 * WLD + kt * 32);
#pragma unroll
            for (int ni = 0; ni < 4; ++ni)
                b[ni] = *(const bf16x8*)(wbase + ni * 16 * WLD + kt * 32);
#pragma unroll
            for (int mi = 0; mi < 4; ++mi)
#pragma unroll
                for (int ni = 0; ni < 4; ++ni)
                    acc1[mi][ni] = __builtin_amdgcn_mfma_f32_16x16x32_bf16(a[mi], b[ni], acc1[mi][ni], 0, 0, 0);
        }

        float b1v[4];
#pragma unroll
        for (int ni = 0; ni < 4; ++ni) b1v[ni] = b1[n0w + ni * 16 + lrow];
#pragma unroll
        for (int mi = 0; mi < 4; ++mi)
#pragma unroll
            for (int ni = 0; ni < 4; ++ni)
#pragma unroll
                for (int reg = 0; reg < 4; ++reg) {
                    int row = mi * 16 + lkg * 4 + reg;
                    int col = n0w + ni * 16 + lrow;
                    G[row][col] = f2bf(gelu_exact(acc1[mi][ni][reg] + b1v[ni]));
                }
    }
    __syncthreads();

    // ---- GEMM2: [64][256] x [256][128] ----
    float* R = (float*)&U[0][0];   // overlay: [64][132] f32
    {
        f32x4 acc2[4][2];
#pragma unroll
        for (int mi = 0; mi < 4; ++mi)
#pragma unroll
            for (int ni = 0; ni < 2; ++ni) acc2[mi][ni] = (f32x4){0.f, 0.f, 0.f, 0.f};

        const short* xbase = &G[lrow][lkg * 8];
        const short* wbase = W2T + (size_t)(wv * 32 + lrow) * WLD + lkg * 8;
#pragma unroll
        for (int kt = 0; kt < 8; ++kt) {
            bf16x8 a[4], b[2];
#pragma unroll
            for (int mi = 0; mi < 4; ++mi)
                a[mi] = *(const bf16x8*)(xbase + mi * 16 * WLD + kt * 32);
#pragma unroll
            for (int ni = 0; ni < 2; ++ni)
                b[ni] = *(const bf16x8*)(wbase + ni * 16 * WLD + kt * 32);
#pragma unroll
            for (int mi = 0; mi < 4; ++mi)
#pragma unroll
                for (int ni = 0; ni < 2; ++ni)
                    acc2[mi][ni] = __builtin_amdgcn_mfma_f32_16x16x32_bf16(a[mi], b[ni], acc2[mi][ni], 0, 0, 0);
        }

        float b2v[2];
#pragma unroll
        for (int ni = 0; ni < 2; ++ni) b2v[ni] = b2[wv * 32 + ni * 16 + lrow];
#pragma unroll
        for (int mi = 0; mi < 4; ++mi)
#pragma unroll
            for (int ni = 0; ni < 2; ++ni)
#pragma unroll
                for (int reg = 0; reg < 4; ++reg) {
                    int row = mi * 16 + lkg * 4 + reg;
                    int col = wv * 32 + ni * 16 + lrow;
                    R[row * 132 + col] = acc2[mi][ni][reg] + b2v[ni];
                }
    }
    __syncthreads();

    // ---- residual + LayerNorm: wave per node ----
#pragma unroll 4
    for (int ii = 0; ii < 16; ++ii) {
        int nl = wv * 16 + ii;
        int gn = n0 + nl;
        int gnc = min(gn, NNODE - 1);
        float rx = R[nl * 132 + lane * 2 + 0];
        float ry = R[nl * 132 + lane * 2 + 1];
        const float2 hh = *(const float2*)(h + (size_t)gnc * DIM + lane * 2);
        float vx = rx + hh.x, vy = ry + hh.y;
        float s = vx + vy;
#pragma unroll
        for (int off = 32; off > 0; off >>= 1) s += __shfl_xor(s, off);
        float mu = s * (1.0f / 128.0f);
        float dx = vx - mu, dy = vy - mu;
        float q = dx * dx + dy * dy;
#pragma unroll
        for (int off = 32; off > 0; off >>= 1) q += __shfl_xor(q, off);
        float inv = rsqrtf(q * (1.0f / 128.0f) + 1e-5f);
        if (gn < NNODE) {
            const float2 gg = *(const float2*)(lng + lane * 2);
            const float2 bb = *(const float2*)(lnb + lane * 2);
            float2 o;
            o.x = dx * inv * gg.x + bb.x;
            o.y = dy * inv * gg.y + bb.y;
            *(float2*)(hout + (size_t)gn * DIM + lane * 2) = o;
        }
    }
}

extern "C" void kernel_launch(void* const* d_in, const int* in_sizes, int n_in,
                              void* d_out, int out_size, void* d_ws, size_t ws_size,
                              hipStream_t stream) {
    const float* h0   = (const float*)d_in[0];
    const int*   ei   = (const int*)d_in[1];
    const float* attr = (const float*)d_in[2];
    const float* ew1  = (const float*)d_in[3];
    const float* eb1  = (const float*)d_in[4];
    const float* ew2  = (const float*)d_in[5];
    const float* eb2  = (const float*)d_in[6];
    const float* nw1  = (const float*)d_in[7];
    const float* nb1  = (const float*)d_in[8];
    const float* nw2  = (const float*)d_in[9];
    const float* nb2  = (const float*)d_in[10];
    const float* lng  = (const float*)d_in[11];
    const float* lnb  = (const float*)d_in[12];

    float* hout = (float*)d_out;
    float* agg  = (float*)d_ws;                         // N*128 f32
    float* den  = agg + (size_t)NNODE * DIM;            // N f32
    short* eW1T = (short*)(den + NNODE);                // [L][256][WLD]
    short* nW1T = eW1T + (size_t)NLAYERS * 256 * WLD;
    short* nW2T = nW1T + (size_t)NLAYERS * 256 * WLD;

    prep_weights<<<1280, 256, 0, stream>>>(ew1, nw1, nw2, eW1T, nW1T, nW2T);

    for (int L = 0; L < NLAYERS; ++L) {
        hipMemsetAsync(agg, 0, ((size_t)NNODE * DIM + NNODE) * sizeof(float), stream);
        const float* hin = (L == 0) ? h0 : hout;
        edge_kernel<<<NEDGE / 64, 256, 0, stream>>>(
            hin, ei, attr,
            eW1T + (size_t)L * 256 * WLD,
            ew1 + (size_t)L * 257 * 256 + 256 * 256,
            eb1 + (size_t)L * 256,
            ew2 + (size_t)L * 256, eb2 + L,
            agg, den);
        node_kernel<<<(NNODE + 63) / 64, 256, 0, stream>>>(
            hin, agg, den,
            nW1T + (size_t)L * 256 * WLD, nb1 + (size_t)L * 256,
            nW2T + (size_t)L * 128 * WLD, nb2 + (size_t)L * 128,
            lng + (size_t)L * DIM, lnb + (size_t)L * DIM,
            hout);
    }
}

// Round 3
// 1073.902 us; speedup vs baseline: 3.7279x; 2.2727x over previous
//
#include <hip/hip_runtime.h>
#include <math.h>

#define NNODE 100000
#define NEDGE 600000
#define DIM 128
#define HID 256
#define NLAYERS 2

typedef short bf16x8 __attribute__((ext_vector_type(8)));
typedef short bf16x4 __attribute__((ext_vector_type(4)));
typedef float f32x4 __attribute__((ext_vector_type(4)));

#define WLD 264  // leading dim (bf16 elems) for transposed weights & LDS tiles

__device__ __forceinline__ short f2bf(float x) {
    union { float f; unsigned u; } v; v.f = x;
    unsigned r = v.u + 0x7FFFu + ((v.u >> 16) & 1u);
    return (short)(r >> 16);
}
__device__ __forceinline__ float bf2f(short s) {
    union { unsigned u; float f; } v; v.u = ((unsigned)(unsigned short)s) << 16;
    return v.f;
}
__device__ __forceinline__ float gelu_exact(float x) {
    return 0.5f * x * (1.0f + erff(x * 0.70710678118654752f));
}

// ---------------- prep: transpose + convert weights to bf16 [n][k] ----------------
__global__ void prep_weights(const float* __restrict__ ew1,
                             const float* __restrict__ nw1,
                             const float* __restrict__ nw2,
                             short* __restrict__ eW1T,
                             short* __restrict__ nW1T,
                             short* __restrict__ nW2T)
{
    int idx = blockIdx.x * 256 + threadIdx.x;
    const int SZ1 = NLAYERS * 256 * 256;
    const int SZ2 = NLAYERS * 256 * 256;
    const int SZ3 = NLAYERS * 128 * 256;
    if (idx < SZ1) {
        int L = idx >> 16, r = idx & 65535, n = r >> 8, k = r & 255;
        eW1T[(size_t)L * 256 * WLD + n * WLD + k] = f2bf(ew1[(size_t)L * 257 * 256 + k * 256 + n]);
        return;
    }
    idx -= SZ1;
    if (idx < SZ2) {
        int L = idx >> 16, r = idx & 65535, n = r >> 8, k = r & 255;
        nW1T[(size_t)L * 256 * WLD + n * WLD + k] = f2bf(nw1[(size_t)L * 256 * 256 + k * 256 + n]);
        return;
    }
    idx -= SZ2;
    if (idx < SZ3) {
        int L = idx >> 15, r = idx & 32767, n = r >> 8, k = r & 255;
        nW2T[(size_t)L * 128 * WLD + n * WLD + k] = f2bf(nw2[(size_t)L * 256 * 128 + k * 128 + n]);
    }
}

// ---------------- h -> bf16 ----------------
__global__ void h2bf(const float* __restrict__ hin, short* __restrict__ hb) {
    int i = blockIdx.x * 256 + threadIdx.x;
    if (i >= NNODE * DIM / 8) return;
    const float4* p = (const float4*)(hin + (size_t)i * 8);
    float4 a = p[0], b = p[1];
    bf16x8 t;
    t[0] = f2bf(a.x); t[1] = f2bf(a.y); t[2] = f2bf(a.z); t[3] = f2bf(a.w);
    t[4] = f2bf(b.x); t[5] = f2bf(b.y); t[6] = f2bf(b.z); t[7] = f2bf(b.w);
    *(bf16x8*)(hb + (size_t)i * 8) = t;
}

// ---------------- CSR build ----------------
__global__ void csr_hist(const int* __restrict__ ei, int* __restrict__ deg) {
    int e = blockIdx.x * 256 + threadIdx.x;
    if (e >= NEDGE) return;
    atomicAdd(&deg[ei[2 * e + 1]], 1);
}

__global__ __launch_bounds__(1024)
void csr_scan(const int* __restrict__ deg, int* __restrict__ rowptr, int* __restrict__ cursor) {
    __shared__ int wsum[16];
    __shared__ int carry_s;
    const int tid = threadIdx.x, lane = tid & 63, wv = tid >> 6;
    if (tid == 0) carry_s = 0;
    __syncthreads();
    for (int base = 0; base < NNODE; base += 1024) {
        int i = base + tid;
        int v = (i < NNODE) ? deg[i] : 0;
        int x = v;
#pragma unroll
        for (int off = 1; off < 64; off <<= 1) {
            int y = __shfl_up(x, off);
            if (lane >= off) x += y;
        }
        if (lane == 63) wsum[wv] = x;
        __syncthreads();
        if (wv == 0) {
            int s = (lane < 16) ? wsum[lane] : 0;
#pragma unroll
            for (int off = 1; off < 16; off <<= 1) {
                int y = __shfl_up(s, off);
                if (lane >= off) s += y;
            }
            if (lane < 16) wsum[lane] = s;
        }
        __syncthreads();
        int carry = carry_s;
        int woff = wv ? wsum[wv - 1] : 0;
        int excl = carry + woff + (x - v);
        if (i < NNODE) { rowptr[i] = excl; cursor[i] = excl; }
        int total = wsum[15];
        __syncthreads();
        if (tid == 0) carry_s = carry + total;
        __syncthreads();
    }
    if (tid == 0) rowptr[NNODE] = carry_s;
}

__global__ void csr_scatter(const int* __restrict__ ei, int* __restrict__ cursor,
                            int* __restrict__ epos, int* __restrict__ esrc) {
    int e = blockIdx.x * 256 + threadIdx.x;
    if (e >= NEDGE) return;
    int s = ei[2 * e], d = ei[2 * e + 1];
    int pos = atomicAdd(&cursor[d], 1);
    epos[e] = pos;
    esrc[pos] = s;
}

// ---------------- Edge kernel: gate only, no scatter ----------------
__global__ __launch_bounds__(256, 4)
void edge_kernel(const short* __restrict__ hb,     // [N][128] bf16
                 const int* __restrict__ ei,
                 const float* __restrict__ attr,
                 const short* __restrict__ W1T,    // [256][WLD]
                 const float* __restrict__ W1a,    // attr row k=256, [256]
                 const float* __restrict__ b1,
                 const float* __restrict__ W2,
                 const float* __restrict__ b2,
                 const int* __restrict__ epos,
                 float* __restrict__ gate_c)       // CSR-ordered gates
{
    __shared__ short Xb[64][WLD];
    __shared__ float glog[64];
    __shared__ float attr_s[64];

    const int tid = threadIdx.x;
    const int e0 = blockIdx.x * 64;

    if (tid < 64) {
        glog[tid] = 0.f;
        attr_s[tid] = attr[e0 + tid];
    }

    for (int idx = tid; idx < 64 * 32; idx += 256) {
        int e = idx >> 5, q = idx & 31;
        int node = ei[2 * (e0 + e) + (q >= 16 ? 1 : 0)];
        *(bf16x8*)&Xb[e][(q & 15) * 8 + (q >= 16 ? 128 : 0)] =
            *(const bf16x8*)(hb + (size_t)node * DIM + (q & 15) * 8);
    }
    __syncthreads();

    const int lane = tid & 63;
    const int wv = tid >> 6;
    const int n0 = wv * 64;
    const int lrow = lane & 15;
    const int lkg = lane >> 4;

    f32x4 acc[4][4];
#pragma unroll
    for (int mi = 0; mi < 4; ++mi)
#pragma unroll
        for (int ni = 0; ni < 4; ++ni) acc[mi][ni] = (f32x4){0.f, 0.f, 0.f, 0.f};

    const short* xbase = &Xb[lrow][lkg * 8];
    const short* wbase = W1T + (size_t)(n0 + lrow) * WLD + lkg * 8;

#pragma unroll
    for (int kt = 0; kt < 8; ++kt) {
        bf16x8 a[4], b[4];
#pragma unroll
        for (int mi = 0; mi < 4; ++mi)
            a[mi] = *(const bf16x8*)(xbase + mi * 16 * WLD + kt * 32);
#pragma unroll
        for (int ni = 0; ni < 4; ++ni)
            b[ni] = *(const bf16x8*)(wbase + ni * 16 * WLD + kt * 32);
#pragma unroll
        for (int mi = 0; mi < 4; ++mi)
#pragma unroll
            for (int ni = 0; ni < 4; ++ni)
                acc[mi][ni] = __builtin_amdgcn_mfma_f32_16x16x32_bf16(a[mi], b[ni], acc[mi][ni], 0, 0, 0);
    }

    float b1v[4], w1av[4], w2v[4];
#pragma unroll
    for (int ni = 0; ni < 4; ++ni) {
        int col = n0 + ni * 16 + lrow;
        b1v[ni] = b1[col]; w1av[ni] = W1a[col]; w2v[ni] = W2[col];
    }
#pragma unroll
    for (int mi = 0; mi < 4; ++mi) {
#pragma unroll
        for (int reg = 0; reg < 4; ++reg) {
            int e = mi * 16 + lkg * 4 + reg;
            float ae = attr_s[e];
            float partial = 0.f;
#pragma unroll
            for (int ni = 0; ni < 4; ++ni) {
                float p = gelu_exact(acc[mi][ni][reg] + b1v[ni] + ae * w1av[ni]);
                partial = fmaf(p, w2v[ni], partial);
            }
            partial += __shfl_xor(partial, 1);
            partial += __shfl_xor(partial, 2);
            partial += __shfl_xor(partial, 4);
            partial += __shfl_xor(partial, 8);
            if (lrow == 0) atomicAdd(&glog[e], partial);
        }
    }
    __syncthreads();

    if (tid < 64) {
        float g = 1.f / (1.f + expf(-(glog[tid] + b2[0])));
        gate_c[epos[e0 + tid]] = g;
    }
}

// ---------------- Node kernel: CSR gather-aggregate + fused MLP + LN ----------------
__global__ __launch_bounds__(256, 2)
void node_kernel(const float* __restrict__ h,       // f32 residual
                 const short* __restrict__ hb,      // bf16 gather source
                 const float* __restrict__ gate_c,  // CSR order
                 const int* __restrict__ rowptr,
                 const int* __restrict__ esrc,      // CSR order
                 const short* __restrict__ W1T,
                 const float* __restrict__ b1,
                 const short* __restrict__ W2T,
                 const float* __restrict__ b2,
                 const float* __restrict__ lng,
                 const float* __restrict__ lnb,
                 float* __restrict__ hout)
{
    __shared__ short U[64][WLD];   // bf16 [node][h | agg]; overlaid later by R f32 [64][132]
    __shared__ short G[64][WLD];

    const int tid = threadIdx.x;
    const int n0 = blockIdx.x * 64;
    const int lane = tid & 63;
    const int wv = tid >> 6;

    // stage h part of U (cols 0..127), straight bf16 copy
    for (int idx = tid; idx < 64 * 16; idx += 256) {
        int nl = idx >> 4, q = idx & 15;
        int gn = min(n0 + nl, NNODE - 1);
        *(bf16x8*)&U[nl][q * 8] = *(const bf16x8*)(hb + (size_t)gn * DIM + q * 8);
    }

    // aggregate: wave wv handles nodes wv*16 .. wv*16+15
    for (int ii = 0; ii < 16; ++ii) {
        int nl = wv * 16 + ii;
        int gn = min(n0 + nl, NNODE - 1);
        int beg = rowptr[gn], end = rowptr[gn + 1];
        int d = end - beg;
        int srcl = 0; float gl = 0.f;
        if (lane < d) { srcl = esrc[beg + lane]; gl = gate_c[beg + lane]; }
        float ax = 0.f, ay = 0.f, den = 0.f;
        int dmax = min(d, 64);
        for (int t = 0; t < dmax; ++t) {
            int src = __shfl(srcl, t);
            float g = __shfl(gl, t);
            unsigned hv = *(const unsigned*)(hb + (size_t)src * DIM + lane * 2);
            ax = fmaf(g, bf2f((short)(hv & 0xFFFFu)), ax);
            ay = fmaf(g, bf2f((short)(hv >> 16)), ay);
            den += g;
        }
        for (int t = 64; t < d; ++t) {   // ultra-rare tail
            int src = esrc[beg + t];
            float g = gate_c[beg + t];
            unsigned hv = *(const unsigned*)(hb + (size_t)src * DIM + lane * 2);
            ax = fmaf(g, bf2f((short)(hv & 0xFFFFu)), ax);
            ay = fmaf(g, bf2f((short)(hv >> 16)), ay);
            den += g;
        }
        float dinv = 1.f / fmaxf(den, 1e-6f);
        unsigned pk = ((unsigned)(unsigned short)f2bf(ay * dinv) << 16) |
                      (unsigned)(unsigned short)f2bf(ax * dinv);
        *(unsigned*)&U[nl][128 + lane * 2] = pk;
    }
    __syncthreads();

    const int lrow = lane & 15;
    const int lkg = lane >> 4;

    // ---- GEMM1: [64][256] x [256][256] ----
    {
        const int n0w = wv * 64;
        f32x4 acc1[4][4];
#pragma unroll
        for (int mi = 0; mi < 4; ++mi)
#pragma unroll
            for (int ni = 0; ni < 4; ++ni) acc1[mi][ni] = (f32x4){0.f, 0.f, 0.f, 0.f};

        const short* xbase = &U[lrow][lkg * 8];
        const short* wbase = W1T + (size_t)(n0w + lrow) * WLD + lkg * 8;
#pragma unroll
        for (int kt = 0; kt < 8; ++kt) {
            bf16x8 a[4], b[4];
#pragma unroll
            for (int mi = 0; mi < 4; ++mi)
                a[mi] = *(const bf16x8*)(xbase + mi * 16 * WLD + kt * 32);
#pragma unroll
            for (int ni = 0; ni < 4; ++ni)
                b[ni] = *(const bf16x8*)(wbase + ni * 16 * WLD + kt * 32);
#pragma unroll
            for (int mi = 0; mi < 4; ++mi)
#pragma unroll
                for (int ni = 0; ni < 4; ++ni)
                    acc1[mi][ni] = __builtin_amdgcn_mfma_f32_16x16x32_bf16(a[mi], b[ni], acc1[mi][ni], 0, 0, 0);
        }

        float b1v[4];
#pragma unroll
        for (int ni = 0; ni < 4; ++ni) b1v[ni] = b1[n0w + ni * 16 + lrow];
#pragma unroll
        for (int mi = 0; mi < 4; ++mi)
#pragma unroll
            for (int ni = 0; ni < 4; ++ni)
#pragma unroll
                for (int reg = 0; reg < 4; ++reg) {
                    int row = mi * 16 + lkg * 4 + reg;
                    int col = n0w + ni * 16 + lrow;
                    G[row][col] = f2bf(gelu_exact(acc1[mi][ni][reg] + b1v[ni]));
                }
    }
    __syncthreads();

    // ---- GEMM2: [64][256] x [256][128] ----
    float* R = (float*)&U[0][0];   // overlay: [64][132] f32
    {
        f32x4 acc2[4][2];
#pragma unroll
        for (int mi = 0; mi < 4; ++mi)
#pragma unroll
            for (int ni = 0; ni < 2; ++ni) acc2[mi][ni] = (f32x4){0.f, 0.f, 0.f, 0.f};

        const short* xbase = &G[lrow][lkg * 8];
        const short* wbase = W2T + (size_t)(wv * 32 + lrow) * WLD + lkg * 8;
#pragma unroll
        for (int kt = 0; kt < 8; ++kt) {
            bf16x8 a[4], b[2];
#pragma unroll
            for (int mi = 0; mi < 4; ++mi)
                a[mi] = *(const bf16x8*)(xbase + mi * 16 * WLD + kt * 32);
#pragma unroll
            for (int ni = 0; ni < 2; ++ni)
                b[ni] = *(const bf16x8*)(wbase + ni * 16 * WLD + kt * 32);
#pragma unroll
            for (int mi = 0; mi < 4; ++mi)
#pragma unroll
                for (int ni = 0; ni < 2; ++ni)
                    acc2[mi][ni] = __builtin_amdgcn_mfma_f32_16x16x32_bf16(a[mi], b[ni], acc2[mi][ni], 0, 0, 0);
        }

        float b2v[2];
#pragma unroll
        for (int ni = 0; ni < 2; ++ni) b2v[ni] = b2[wv * 32 + ni * 16 + lrow];
#pragma unroll
        for (int mi = 0; mi < 4; ++mi)
#pragma unroll
            for (int ni = 0; ni < 2; ++ni)
#pragma unroll
                for (int reg = 0; reg < 4; ++reg) {
                    int row = mi * 16 + lkg * 4 + reg;
                    int col = wv * 32 + ni * 16 + lrow;
                    R[row * 132 + col] = acc2[mi][ni][reg] + b2v[ni];
                }
    }
    __syncthreads();

    // ---- residual + LayerNorm ----
#pragma unroll 4
    for (int ii = 0; ii < 16; ++ii) {
        int nl = wv * 16 + ii;
        int gn = n0 + nl;
        int gnc = min(gn, NNODE - 1);
        float rx = R[nl * 132 + lane * 2 + 0];
        float ry = R[nl * 132 + lane * 2 + 1];
        const float2 hh = *(const float2*)(h + (size_t)gnc * DIM + lane * 2);
        float vx = rx + hh.x, vy = ry + hh.y;
        float s = vx + vy;
#pragma unroll
        for (int off = 32; off > 0; off >>= 1) s += __shfl_xor(s, off);
        float mu = s * (1.0f / 128.0f);
        float dx = vx - mu, dy = vy - mu;
        float q = dx * dx + dy * dy;
#pragma unroll
        for (int off = 32; off > 0; off >>= 1) q += __shfl_xor(q, off);
        float inv = rsqrtf(q * (1.0f / 128.0f) + 1e-5f);
        if (gn < NNODE) {
            const float2 gg = *(const float2*)(lng + lane * 2);
            const float2 bb = *(const float2*)(lnb + lane * 2);
            float2 o;
            o.x = dx * inv * gg.x + bb.x;
            o.y = dy * inv * gg.y + bb.y;
            *(float2*)(hout + (size_t)gn * DIM + lane * 2) = o;
        }
    }
}

extern "C" void kernel_launch(void* const* d_in, const int* in_sizes, int n_in,
                              void* d_out, int out_size, void* d_ws, size_t ws_size,
                              hipStream_t stream) {
    const float* h0   = (const float*)d_in[0];
    const int*   ei   = (const int*)d_in[1];
    const float* attr = (const float*)d_in[2];
    const float* ew1  = (const float*)d_in[3];
    const float* eb1  = (const float*)d_in[4];
    const float* ew2  = (const float*)d_in[5];
    const float* eb2  = (const float*)d_in[6];
    const float* nw1  = (const float*)d_in[7];
    const float* nb1  = (const float*)d_in[8];
    const float* nw2  = (const float*)d_in[9];
    const float* nb2  = (const float*)d_in[10];
    const float* lng  = (const float*)d_in[11];
    const float* lnb  = (const float*)d_in[12];

    float* hout = (float*)d_out;

    float* gate_c = (float*)d_ws;                     // E
    int*   rowptr = (int*)(gate_c + NEDGE);           // N+1
    int*   cursor = rowptr + NNODE + 1;               // N+1
    int*   deg    = cursor + NNODE + 1;               // N+1
    int*   epos   = deg + NNODE + 1;                  // E
    int*   esrc   = epos + NEDGE;                     // E
    short* hb     = (short*)(esrc + NEDGE);           // N*DIM bf16
    short* eW1T   = hb + (size_t)NNODE * DIM;
    short* nW1T   = eW1T + (size_t)NLAYERS * 256 * WLD;
    short* nW2T   = nW1T + (size_t)NLAYERS * 256 * WLD;

    hipMemsetAsync(deg, 0, (NNODE + 1) * sizeof(int), stream);
    prep_weights<<<1280, 256, 0, stream>>>(ew1, nw1, nw2, eW1T, nW1T, nW2T);
    csr_hist<<<(NEDGE + 255) / 256, 256, 0, stream>>>(ei, deg);
    csr_scan<<<1, 1024, 0, stream>>>(deg, rowptr, cursor);
    csr_scatter<<<(NEDGE + 255) / 256, 256, 0, stream>>>(ei, cursor, epos, esrc);

    for (int L = 0; L < NLAYERS; ++L) {
        const float* hin = (L == 0) ? h0 : hout;
        h2bf<<<(NNODE * DIM / 8 + 255) / 256, 256, 0, stream>>>(hin, hb);
        edge_kernel<<<NEDGE / 64, 256, 0, stream>>>(
            hb, ei, attr,
            eW1T + (size_t)L * 256 * WLD,
            ew1 + (size_t)L * 257 * 256 + 256 * 256,
            eb1 + (size_t)L * 256,
            ew2 + (size_t)L * 256, eb2 + L,
            epos, gate_c);
        node_kernel<<<(NNODE + 63) / 64, 256, 0, stream>>>(
            hin, hb, gate_c, rowptr, esrc,
            nW1T + (size_t)L * 256 * WLD, nb1 + (size_t)L * 256,
            nW2T + (size_t)L * 128 * WLD, nb2 + (size_t)L * 128,
            lng + (size_t)L * DIM, lnb + (size_t)L * DIM,
            hout);
    }
}

// Round 4
// 742.545 us; speedup vs baseline: 5.3915x; 1.4462x over previous
//
#include <hip/hip_runtime.h>
#include <math.h>

#define NNODE 100000
#define NEDGE 600000
#define DIM 128
#define HID 256
#define NLAYERS 2

typedef short bf16x8 __attribute__((ext_vector_type(8)));
typedef short bf16x4 __attribute__((ext_vector_type(4)));
typedef float f32x4 __attribute__((ext_vector_type(4)));

#define WK 136    // proj weight LD (k=128 + pad)
#define WLD 264   // node weight / LDS tile LD (k=256 + pad)

__device__ __forceinline__ short f2bf(float x) {
    union { float f; unsigned u; } v; v.f = x;
    unsigned r = v.u + 0x7FFFu + ((v.u >> 16) & 1u);
    return (short)(r >> 16);
}
__device__ __forceinline__ float bf2f(short s) {
    union { unsigned u; float f; } v; v.u = ((unsigned)(unsigned short)s) << 16;
    return v.f;
}
// gelu via A&S 7.1.26 erf (abs err ~1.5e-7)
__device__ __forceinline__ float gelu_erf(float x) {
    float z = x * 0.70710678118654752f;
    float az = fabsf(z);
    float t = __builtin_amdgcn_rcpf(1.0f + 0.3275911f * az);
    float y = t * (0.254829592f + t * (-0.284496736f + t * (1.421413741f +
              t * (-1.453152027f + t * 1.061405429f))));
    float e = __expf(-az * az);
    float er = 1.0f - y * e;
    er = copysignf(er, z);
    return 0.5f * x * (1.0f + er);
}

// ---------------- prep: weights -> bf16 transposed ----------------
__global__ void prep_weights(const float* __restrict__ ew1,   // [L][257][256]
                             const float* __restrict__ nw1,   // [L][256][256]
                             const float* __restrict__ nw2,   // [L][256][128]
                             short* __restrict__ pW,          // [L][512][WK]: r<256 Ps col r (k=0..127), r>=256 Pd col r-256 (k=128..255)
                             short* __restrict__ nW1T,        // [L][256][WLD]
                             short* __restrict__ nW2T)        // [L][128][WLD]
{
    int idx = blockIdx.x * 256 + threadIdx.x;
    const int SZ1 = NLAYERS * 512 * 128;
    const int SZ2 = NLAYERS * 256 * 256;
    const int SZ3 = NLAYERS * 128 * 256;
    if (idx < SZ1) {
        int L = idx / (512 * 128); int rr = idx - L * 512 * 128;
        int r = rr >> 7, k = rr & 127;
        int srow = (r < 256) ? k : 128 + k;
        int scol = (r < 256) ? r : r - 256;
        pW[(size_t)L * 512 * WK + r * WK + k] = f2bf(ew1[(size_t)L * 257 * 256 + srow * 256 + scol]);
        return;
    }
    idx -= SZ1;
    if (idx < SZ2) {
        int L = idx >> 16, r = idx & 65535, n = r >> 8, k = r & 255;
        nW1T[(size_t)L * 256 * WLD + n * WLD + k] = f2bf(nw1[(size_t)L * 256 * 256 + k * 256 + n]);
        return;
    }
    idx -= SZ2;
    if (idx < SZ3) {
        int L = idx >> 15, r = idx & 32767, n = r >> 8, k = r & 255;
        nW2T[(size_t)L * 128 * WLD + n * WLD + k] = f2bf(nw2[(size_t)L * 256 * 128 + k * 128 + n]);
    }
}

// ---------------- h -> bf16 (layer 0 only) ----------------
__global__ void h2bf(const float* __restrict__ hin, short* __restrict__ hb) {
    int i = blockIdx.x * 256 + threadIdx.x;
    if (i >= NNODE * DIM / 8) return;
    const float4* p = (const float4*)(hin + (size_t)i * 8);
    float4 a = p[0], b = p[1];
    bf16x8 t;
    t[0] = f2bf(a.x); t[1] = f2bf(a.y); t[2] = f2bf(a.z); t[3] = f2bf(a.w);
    t[4] = f2bf(b.x); t[5] = f2bf(b.y); t[6] = f2bf(b.z); t[7] = f2bf(b.w);
    *(bf16x8*)(hb + (size_t)i * 8) = t;
}

// ---------------- CSR build ----------------
__global__ void csr_hist(const int* __restrict__ ei, int* __restrict__ deg) {
    int e = blockIdx.x * 256 + threadIdx.x;
    if (e >= NEDGE) return;
    atomicAdd(&deg[ei[2 * e + 1]], 1);
}

__global__ __launch_bounds__(1024)
void csr_scan(const int* __restrict__ deg, int* __restrict__ rowptr, int* __restrict__ cursor) {
    __shared__ int wsum[16];
    __shared__ int carry_s;
    const int tid = threadIdx.x, lane = tid & 63, wv = tid >> 6;
    if (tid == 0) carry_s = 0;
    __syncthreads();
    for (int base = 0; base < NNODE; base += 1024) {
        int i = base + tid;
        int v = (i < NNODE) ? deg[i] : 0;
        int x = v;
#pragma unroll
        for (int off = 1; off < 64; off <<= 1) {
            int y = __shfl_up(x, off);
            if (lane >= off) x += y;
        }
        if (lane == 63) wsum[wv] = x;
        __syncthreads();
        if (wv == 0) {
            int s = (lane < 16) ? wsum[lane] : 0;
#pragma unroll
            for (int off = 1; off < 16; off <<= 1) {
                int y = __shfl_up(s, off);
                if (lane >= off) s += y;
            }
            if (lane < 16) wsum[lane] = s;
        }
        __syncthreads();
        int carry = carry_s;
        int woff = wv ? wsum[wv - 1] : 0;
        int excl = carry + woff + (x - v);
        if (i < NNODE) { rowptr[i] = excl; cursor[i] = excl; }
        int total = wsum[15];
        __syncthreads();
        if (tid == 0) carry_s = carry + total;
        __syncthreads();
    }
    if (tid == 0) rowptr[NNODE] = carry_s;
}

__global__ void csr_scatter(const int* __restrict__ ei, const float* __restrict__ attr,
                            int* __restrict__ cursor,
                            int* __restrict__ esrc, int* __restrict__ edst,
                            float* __restrict__ attr_c) {
    int e = blockIdx.x * 256 + threadIdx.x;
    if (e >= NEDGE) return;
    int s = ei[2 * e], d = ei[2 * e + 1];
    int pos = atomicAdd(&cursor[d], 1);
    esrc[pos] = s;
    edst[pos] = d;
    attr_c[pos] = attr[e];
}

// ---------------- proj: Ps = h@W1s, Pd = h@W1d ----------------
__global__ __launch_bounds__(512, 2)
void proj_kernel(const short* __restrict__ hb,   // [N][128] bf16
                 const short* __restrict__ pW,   // [512][WK]
                 short* __restrict__ Ps,         // [N][256]
                 short* __restrict__ Pd)         // [N][256]
{
    __shared__ short A[64][WK];
    const int tid = threadIdx.x;
    const int n0 = blockIdx.x * 64;

    for (int idx = tid; idx < 64 * 16; idx += 512) {
        int nl = idx >> 4, q = idx & 15;
        int gn = min(n0 + nl, NNODE - 1);
        *(bf16x8*)&A[nl][q * 8] = *(const bf16x8*)(hb + (size_t)gn * DIM + q * 8);
    }
    __syncthreads();

    const int lane = tid & 63;
    const int wv = tid >> 6;     // 0..7; wv<4 -> Ps cols, wv>=4 -> Pd cols
    const int lrow = lane & 15;
    const int lkg = lane >> 4;

    f32x4 acc[4][4];
#pragma unroll
    for (int mi = 0; mi < 4; ++mi)
#pragma unroll
        for (int ni = 0; ni < 4; ++ni) acc[mi][ni] = (f32x4){0.f, 0.f, 0.f, 0.f};

    const short* xbase = &A[lrow][lkg * 8];
    const short* wbase = pW + (size_t)(wv * 64 + lrow) * WK + lkg * 8;

#pragma unroll
    for (int kt = 0; kt < 4; ++kt) {
        bf16x8 a[4], b[4];
#pragma unroll
        for (int mi = 0; mi < 4; ++mi)
            a[mi] = *(const bf16x8*)(xbase + mi * 16 * WK + kt * 32);
#pragma unroll
        for (int ni = 0; ni < 4; ++ni)
            b[ni] = *(const bf16x8*)(wbase + ni * 16 * WK + kt * 32);
#pragma unroll
        for (int mi = 0; mi < 4; ++mi)
#pragma unroll
            for (int ni = 0; ni < 4; ++ni)
                acc[mi][ni] = __builtin_amdgcn_mfma_f32_16x16x32_bf16(a[mi], b[ni], acc[mi][ni], 0, 0, 0);
    }

    short* dstP = (wv < 4) ? Ps : Pd;
    const int colbase = (wv & 3) * 64;
#pragma unroll
    for (int mi = 0; mi < 4; ++mi)
#pragma unroll
        for (int ni = 0; ni < 4; ++ni) {
            int col = colbase + ni * 16 + lrow;
#pragma unroll
            for (int reg = 0; reg < 4; ++reg) {
                int node = n0 + mi * 16 + lkg * 4 + reg;
                if (node < NNODE)
                    dstP[(size_t)node * 256 + col] = f2bf(acc[mi][ni][reg]);
            }
        }
}

// ---------------- edge gate: per-edge MLP from gathered projections ----------------
__global__ __launch_bounds__(256)
void edge_gate(const short* __restrict__ Ps, const short* __restrict__ Pd,
               const int* __restrict__ esrc, const int* __restrict__ edst,
               const float* __restrict__ attr_c,
               const float* __restrict__ w1a, const float* __restrict__ b1,
               const float* __restrict__ w2, const float* __restrict__ b2,
               float* __restrict__ gate_c)
{
    const int lane = threadIdx.x & 63;
    const int gw = (blockIdx.x * 256 + threadIdx.x) >> 6;
    const int e0 = gw * 32;
    if (e0 >= NEDGE) return;

    const float4 w1av = ((const float4*)w1a)[lane];
    const float4 b1v  = ((const float4*)b1)[lane];
    const float4 w2v  = ((const float4*)w2)[lane];
    const float b2s = b2[0];

    int sl = 0, dl = 0; float al = 0.f;
    if (lane < 32) {
        sl = esrc[e0 + lane];
        dl = edst[e0 + lane];
        al = attr_c[e0 + lane];
    }

#pragma unroll 2
    for (int t = 0; t < 32; ++t) {
        int s = __shfl(sl, t);
        int d = __shfl(dl, t);
        float a = __shfl(al, t);
        bf16x4 ps = *(const bf16x4*)(Ps + (size_t)s * 256 + lane * 4);
        bf16x4 pd = *(const bf16x4*)(Pd + (size_t)d * 256 + lane * 4);
        float x0 = bf2f(ps[0]) + bf2f(pd[0]) + fmaf(a, w1av.x, b1v.x);
        float x1 = bf2f(ps[1]) + bf2f(pd[1]) + fmaf(a, w1av.y, b1v.y);
        float x2 = bf2f(ps[2]) + bf2f(pd[2]) + fmaf(a, w1av.z, b1v.z);
        float x3 = bf2f(ps[3]) + bf2f(pd[3]) + fmaf(a, w1av.w, b1v.w);
        float acc = gelu_erf(x0) * w2v.x + gelu_erf(x1) * w2v.y +
                    gelu_erf(x2) * w2v.z + gelu_erf(x3) * w2v.w;
        acc += __shfl_xor(acc, 1);
        acc += __shfl_xor(acc, 2);
        acc += __shfl_xor(acc, 4);
        acc += __shfl_xor(acc, 8);
        acc += __shfl_xor(acc, 16);
        acc += __shfl_xor(acc, 32);
        if (lane == 0)
            gate_c[e0 + t] = __builtin_amdgcn_rcpf(1.0f + __expf(-(acc + b2s)));
    }
}

// ---------------- agg: CSR gather-aggregate, one wave per node ----------------
__global__ __launch_bounds__(256, 8)
void agg_kernel(const short* __restrict__ hb, const float* __restrict__ gate_c,
                const int* __restrict__ esrc, const int* __restrict__ rowptr,
                short* __restrict__ u2)        // [N][128] bf16 (agg/den)
{
    const int node = (blockIdx.x * 256 + threadIdx.x) >> 6;
    const int lane = threadIdx.x & 63;
    if (node >= NNODE) return;
    int beg = rowptr[node], end = rowptr[node + 1];
    int d = end - beg;
    int srcl = 0; float gl = 0.f;
    if (lane < d) { srcl = esrc[beg + lane]; gl = gate_c[beg + lane]; }
    float ax = 0.f, ay = 0.f, den = 0.f;
    int dm = min(d, 64);
    for (int t = 0; t < dm; ++t) {
        int src = __shfl(srcl, t);
        float g = __shfl(gl, t);
        unsigned hv = *(const unsigned*)(hb + (size_t)src * DIM + lane * 2);
        ax = fmaf(g, bf2f((short)(hv & 0xFFFFu)), ax);
        ay = fmaf(g, bf2f((short)(hv >> 16)), ay);
        den += g;
    }
    for (int t = 64; t < d; ++t) {
        int src = esrc[beg + t];
        float g = gate_c[beg + t];
        unsigned hv = *(const unsigned*)(hb + (size_t)src * DIM + lane * 2);
        ax = fmaf(g, bf2f((short)(hv & 0xFFFFu)), ax);
        ay = fmaf(g, bf2f((short)(hv >> 16)), ay);
        den += g;
    }
    float dinv = __builtin_amdgcn_rcpf(fmaxf(den, 1e-6f));
    // refine rcp (one NR step) for accuracy
    dinv = dinv * (2.0f - fmaxf(den, 1e-6f) * dinv);
    unsigned pk = ((unsigned)(unsigned short)f2bf(ay * dinv) << 16) |
                  (unsigned)(unsigned short)f2bf(ax * dinv);
    *(unsigned*)(u2 + (size_t)node * DIM + lane * 2) = pk;
}

// ---------------- node MLP: 32 nodes/block, fused GEMM1+gelu+GEMM2+LN ----------------
__global__ __launch_bounds__(256, 4)
void node_mlp(const float* __restrict__ hin,   // f32 residual
              const short* __restrict__ hb,    // bf16
              const short* __restrict__ u2,    // bf16 agg
              const short* __restrict__ W1T,   // [256][WLD]
              const float* __restrict__ b1,
              const short* __restrict__ W2T,   // [128][WLD]
              const float* __restrict__ b2,
              const float* __restrict__ lng, const float* __restrict__ lnb,
              float* __restrict__ hout, short* __restrict__ hb_out)
{
    __shared__ short U[32][WLD];
    __shared__ short G[32][WLD];

    const int tid = threadIdx.x;
    const int n0 = blockIdx.x * 32;   // NNODE % 32 == 0
    const int lane = tid & 63;
    const int wv = tid >> 6;

    for (int idx = tid; idx < 32 * 32; idx += 256) {
        int nl = idx >> 5, q = idx & 31;
        const short* src = (q < 16) ? (hb + (size_t)(n0 + nl) * DIM + q * 8)
                                    : (u2 + (size_t)(n0 + nl) * DIM + (q - 16) * 8);
        *(bf16x8*)&U[nl][q * 8] = *(const bf16x8*)src;
    }
    __syncthreads();

    const int lrow = lane & 15;
    const int lkg = lane >> 4;

    // GEMM1: [32][256] x [256][256]
    {
        const int n0w = wv * 64;
        f32x4 acc1[2][4];
#pragma unroll
        for (int mi = 0; mi < 2; ++mi)
#pragma unroll
            for (int ni = 0; ni < 4; ++ni) acc1[mi][ni] = (f32x4){0.f, 0.f, 0.f, 0.f};

        const short* xbase = &U[lrow][lkg * 8];
        const short* wbase = W1T + (size_t)(n0w + lrow) * WLD + lkg * 8;
#pragma unroll
        for (int kt = 0; kt < 8; ++kt) {
            bf16x8 a[2], b[4];
#pragma unroll
            for (int mi = 0; mi < 2; ++mi)
                a[mi] = *(const bf16x8*)(xbase + mi * 16 * WLD + kt * 32);
#pragma unroll
            for (int ni = 0; ni < 4; ++ni)
                b[ni] = *(const bf16x8*)(wbase + ni * 16 * WLD + kt * 32);
#pragma unroll
            for (int mi = 0; mi < 2; ++mi)
#pragma unroll
                for (int ni = 0; ni < 4; ++ni)
                    acc1[mi][ni] = __builtin_amdgcn_mfma_f32_16x16x32_bf16(a[mi], b[ni], acc1[mi][ni], 0, 0, 0);
        }

        float b1v[4];
#pragma unroll
        for (int ni = 0; ni < 4; ++ni) b1v[ni] = b1[n0w + ni * 16 + lrow];
#pragma unroll
        for (int mi = 0; mi < 2; ++mi)
#pragma unroll
            for (int ni = 0; ni < 4; ++ni)
#pragma unroll
                for (int reg = 0; reg < 4; ++reg) {
                    int row = mi * 16 + lkg * 4 + reg;
                    int col = n0w + ni * 16 + lrow;
                    G[row][col] = f2bf(gelu_erf(acc1[mi][ni][reg] + b1v[ni]));
                }
    }
    __syncthreads();

    // GEMM2: [32][256] x [256][128]
    float* R = (float*)&U[0][0];   // overlay [32][132] f32
    {
        f32x4 acc2[2][2];
#pragma unroll
        for (int mi = 0; mi < 2; ++mi)
#pragma unroll
            for (int ni = 0; ni < 2; ++ni) acc2[mi][ni] = (f32x4){0.f, 0.f, 0.f, 0.f};

        const short* xbase = &G[lrow][lkg * 8];
        const short* wbase = W2T + (size_t)(wv * 32 + lrow) * WLD + lkg * 8;
#pragma unroll
        for (int kt = 0; kt < 8; ++kt) {
            bf16x8 a[2], b[2];
#pragma unroll
            for (int mi = 0; mi < 2; ++mi)
                a[mi] = *(const bf16x8*)(xbase + mi * 16 * WLD + kt * 32);
#pragma unroll
            for (int ni = 0; ni < 2; ++ni)
                b[ni] = *(const bf16x8*)(wbase + ni * 16 * WLD + kt * 32);
#pragma unroll
            for (int mi = 0; mi < 2; ++mi)
#pragma unroll
                for (int ni = 0; ni < 2; ++ni)
                    acc2[mi][ni] = __builtin_amdgcn_mfma_f32_16x16x32_bf16(a[mi], b[ni], acc2[mi][ni], 0, 0, 0);
        }

        float b2v[2];
#pragma unroll
        for (int ni = 0; ni < 2; ++ni) b2v[ni] = b2[wv * 32 + ni * 16 + lrow];
#pragma unroll
        for (int mi = 0; mi < 2; ++mi)
#pragma unroll
            for (int ni = 0; ni < 2; ++ni)
#pragma unroll
                for (int reg = 0; reg < 4; ++reg) {
                    int row = mi * 16 + lkg * 4 + reg;
                    int col = wv * 32 + ni * 16 + lrow;
                    R[row * 132 + col] = acc2[mi][ni][reg] + b2v[ni];
                }
    }
    __syncthreads();

    // residual + LayerNorm; write hout f32 + hb bf16
#pragma unroll
    for (int ii = 0; ii < 8; ++ii) {
        int nl = wv * 8 + ii;
        int gn = n0 + nl;
        float rx = R[nl * 132 + lane * 2 + 0];
        float ry = R[nl * 132 + lane * 2 + 1];
        const float2 hh = *(const float2*)(hin + (size_t)gn * DIM + lane * 2);
        float vx = rx + hh.x, vy = ry + hh.y;
        float s = vx + vy;
#pragma unroll
        for (int off = 32; off > 0; off >>= 1) s += __shfl_xor(s, off);
        float mu = s * (1.0f / 128.0f);
        float dx = vx - mu, dy = vy - mu;
        float q = dx * dx + dy * dy;
#pragma unroll
        for (int off = 32; off > 0; off >>= 1) q += __shfl_xor(q, off);
        float inv = rsqrtf(q * (1.0f / 128.0f) + 1e-5f);
        const float2 gg = *(const float2*)(lng + lane * 2);
        const float2 bb = *(const float2*)(lnb + lane * 2);
        float ox = dx * inv * gg.x + bb.x;
        float oy = dy * inv * gg.y + bb.y;
        *(float2*)(hout + (size_t)gn * DIM + lane * 2) = make_float2(ox, oy);
        unsigned pk = ((unsigned)(unsigned short)f2bf(oy) << 16) |
                      (unsigned)(unsigned short)f2bf(ox);
        *(unsigned*)(hb_out + (size_t)gn * DIM + lane * 2) = pk;
    }
}

extern "C" void kernel_launch(void* const* d_in, const int* in_sizes, int n_in,
                              void* d_out, int out_size, void* d_ws, size_t ws_size,
                              hipStream_t stream) {
    const float* h0   = (const float*)d_in[0];
    const int*   ei   = (const int*)d_in[1];
    const float* attr = (const float*)d_in[2];
    const float* ew1  = (const float*)d_in[3];
    const float* eb1  = (const float*)d_in[4];
    const float* ew2  = (const float*)d_in[5];
    const float* eb2  = (const float*)d_in[6];
    const float* nw1  = (const float*)d_in[7];
    const float* nb1  = (const float*)d_in[8];
    const float* nw2  = (const float*)d_in[9];
    const float* nb2  = (const float*)d_in[10];
    const float* lng  = (const float*)d_in[11];
    const float* lnb  = (const float*)d_in[12];

    float* hout = (float*)d_out;

    char* p = (char*)d_ws;
    float* gate_c = (float*)p;             p += sizeof(float) * NEDGE;
    int*   rowptr = (int*)p;               p += sizeof(int) * (NNODE + 1);
    int*   cursor = (int*)p;               p += sizeof(int) * (NNODE + 1);
    int*   deg    = (int*)p;               p += sizeof(int) * (NNODE + 1);
    int*   esrc   = (int*)p;               p += sizeof(int) * NEDGE;
    int*   edst   = (int*)p;               p += sizeof(int) * NEDGE;
    float* attr_c = (float*)p;             p += sizeof(float) * NEDGE;
    short* hb     = (short*)p;             p += sizeof(short) * (size_t)NNODE * DIM;
    short* Ps     = (short*)p;             p += sizeof(short) * (size_t)NNODE * 256;
    short* Pd     = (short*)p;             p += sizeof(short) * (size_t)NNODE * 256;
    short* u2     = Pd;                    // alias: u2 written after Pd's last read
    short* pW     = (short*)p;             p += sizeof(short) * (size_t)NLAYERS * 512 * WK;
    short* nW1T   = (short*)p;             p += sizeof(short) * (size_t)NLAYERS * 256 * WLD;
    short* nW2T   = (short*)p;             p += sizeof(short) * (size_t)NLAYERS * 128 * WLD;

    hipMemsetAsync(deg, 0, (NNODE + 1) * sizeof(int), stream);
    prep_weights<<<1280, 256, 0, stream>>>(ew1, nw1, nw2, pW, nW1T, nW2T);
    csr_hist<<<(NEDGE + 255) / 256, 256, 0, stream>>>(ei, deg);
    csr_scan<<<1, 1024, 0, stream>>>(deg, rowptr, cursor);
    csr_scatter<<<(NEDGE + 255) / 256, 256, 0, stream>>>(ei, attr, cursor, esrc, edst, attr_c);
    h2bf<<<(NNODE * DIM / 8 + 255) / 256, 256, 0, stream>>>(h0, hb);

    for (int L = 0; L < NLAYERS; ++L) {
        const float* hin = (L == 0) ? h0 : hout;
        proj_kernel<<<(NNODE + 63) / 64, 512, 0, stream>>>(
            hb, pW + (size_t)L * 512 * WK, Ps, Pd);
        edge_gate<<<(NEDGE / 32 + 3) / 4, 256, 0, stream>>>(
            Ps, Pd, esrc, edst, attr_c,
            ew1 + (size_t)L * 257 * 256 + 256 * 256,
            eb1 + (size_t)L * 256,
            ew2 + (size_t)L * 256, eb2 + L, gate_c);
        agg_kernel<<<NNODE / 4, 256, 0, stream>>>(hb, gate_c, esrc, rowptr, u2);
        node_mlp<<<NNODE / 32, 256, 0, stream>>>(
            hin, hb, u2,
            nW1T + (size_t)L * 256 * WLD, nb1 + (size_t)L * 256,
            nW2T + (size_t)L * 128 * WLD, nb2 + (size_t)L * 128,
            lng + (size_t)L * DIM, lnb + (size_t)L * DIM,
            hout, hb);
    }
}

// Round 5
// 529.637 us; speedup vs baseline: 7.5589x; 1.4020x over previous
//
#include <hip/hip_runtime.h>
#include <math.h>

#define NNODE 100000
#define NEDGE 600000
#define DIM 128
#define HID 256
#define NLAYERS 2

typedef short bf16x8 __attribute__((ext_vector_type(8)));
typedef short bf16x4 __attribute__((ext_vector_type(4)));
typedef float f32x4 __attribute__((ext_vector_type(4)));

#define WK 136    // proj weight LD (k=128 + pad)
#define WLD 264   // node weight / LDS tile LD (k=256 + pad)

__device__ __forceinline__ short f2bf(float x) {
    union { float f; unsigned u; } v; v.f = x;
    unsigned r = v.u + 0x7FFFu + ((v.u >> 16) & 1u);
    return (short)(r >> 16);
}
__device__ __forceinline__ float bf2f(short s) {
    union { unsigned u; float f; } v; v.u = ((unsigned)(unsigned short)s) << 16;
    return v.f;
}
// accurate gelu (A&S erf) for node MLP
__device__ __forceinline__ float gelu_erf(float x) {
    float z = x * 0.70710678118654752f;
    float az = fabsf(z);
    float t = __builtin_amdgcn_rcpf(1.0f + 0.3275911f * az);
    float y = t * (0.254829592f + t * (-0.284496736f + t * (1.421413741f +
              t * (-1.453152027f + t * 1.061405429f))));
    float e = __expf(-az * az);
    float er = 1.0f - y * e;
    er = copysignf(er, z);
    return 0.5f * x * (1.0f + er);
}
// fast gelu (sigmoid approx) for edge path: x * sigmoid(1.702 x)
__device__ __forceinline__ float gelu_fast(float x) {
    float e = exp2f(-2.4554673f * x);           // exp(-1.702x)
    return x * __builtin_amdgcn_rcpf(1.0f + e);
}
__device__ __forceinline__ float sigmoid_fast(float z) {
    float e = exp2f(-1.4426950408889634f * z);
    return __builtin_amdgcn_rcpf(1.0f + e);
}

// ---------------- prep: weights -> bf16 transposed (+ permuted edge vectors) ----------------
// Hidden-dim storage permutation for Ps/Pd: within each 64-block,
// storage c' = lrow*4 + ni  holds semantic col c = ni*16 + lrow  (ni in [0,4), lrow in [0,16)).
// unswz(c') = (c' & ~63) | ((c'&3)*16 + ((c'>>2)&15))
__global__ void prep_weights(const float* __restrict__ ew1,   // [L][257][256]
                             const float* __restrict__ eb1,   // [L][256]
                             const float* __restrict__ ew2,   // [L][256][1]
                             const float* __restrict__ nw1,   // [L][256][256]
                             const float* __restrict__ nw2,   // [L][256][128]
                             short* __restrict__ pW,          // [L][512][WK]
                             short* __restrict__ nW1T,        // [L][256][WLD]
                             short* __restrict__ nW2T,        // [L][128][WLD]
                             float* __restrict__ w1a_p,       // [L][256] permuted
                             float* __restrict__ b1_p,        // [L][256] permuted
                             float* __restrict__ w2_p)        // [L][256] permuted
{
    int idx = blockIdx.x * 256 + threadIdx.x;
    const int SZ1 = NLAYERS * 512 * 128;
    const int SZ2 = NLAYERS * 256 * 256;
    const int SZ3 = NLAYERS * 128 * 256;
    const int SZ4 = NLAYERS * 256;
    if (idx < SZ1) {
        int L = idx / (512 * 128); int rr = idx - L * 512 * 128;
        int r = rr >> 7, k = rr & 127;
        int srow = (r < 256) ? k : 128 + k;
        int scol = (r < 256) ? r : r - 256;
        pW[(size_t)L * 512 * WK + r * WK + k] = f2bf(ew1[(size_t)L * 257 * 256 + srow * 256 + scol]);
        return;
    }
    idx -= SZ1;
    if (idx < SZ2) {
        int L = idx >> 16, r = idx & 65535, n = r >> 8, k = r & 255;
        nW1T[(size_t)L * 256 * WLD + n * WLD + k] = f2bf(nw1[(size_t)L * 256 * 256 + k * 256 + n]);
        return;
    }
    idx -= SZ2;
    if (idx < SZ3) {
        int L = idx >> 15, r = idx & 32767, n = r >> 8, k = r & 255;
        nW2T[(size_t)L * 128 * WLD + n * WLD + k] = f2bf(nw2[(size_t)L * 256 * 128 + k * 128 + n]);
        return;
    }
    idx -= SZ3;
    if (idx < SZ4) {
        int L = idx >> 8, c = idx & 255;
        int cs = (c & ~63) | ((c & 3) * 16 + ((c >> 2) & 15));
        w1a_p[idx] = ew1[(size_t)L * 257 * 256 + 256 * 256 + cs];
        b1_p[idx]  = eb1[(size_t)L * 256 + cs];
        w2_p[idx]  = ew2[(size_t)L * 256 + cs];
    }
}

// ---------------- h -> bf16 (layer 0 only) ----------------
__global__ void h2bf(const float* __restrict__ hin, short* __restrict__ hb) {
    int i = blockIdx.x * 256 + threadIdx.x;
    if (i >= NNODE * DIM / 8) return;
    const float4* p = (const float4*)(hin + (size_t)i * 8);
    float4 a = p[0], b = p[1];
    bf16x8 t;
    t[0] = f2bf(a.x); t[1] = f2bf(a.y); t[2] = f2bf(a.z); t[3] = f2bf(a.w);
    t[4] = f2bf(b.x); t[5] = f2bf(b.y); t[6] = f2bf(b.z); t[7] = f2bf(b.w);
    *(bf16x8*)(hb + (size_t)i * 8) = t;
}

// ---------------- CSR build ----------------
__global__ void csr_hist(const int* __restrict__ ei, int* __restrict__ deg) {
    int e = blockIdx.x * 256 + threadIdx.x;
    if (e >= NEDGE) return;
    atomicAdd(&deg[ei[2 * e + 1]], 1);
}

__global__ __launch_bounds__(1024)
void csr_scan(const int* __restrict__ deg, int* __restrict__ rowptr, int* __restrict__ cursor) {
    __shared__ int wsum[16];
    __shared__ int carry_s;
    const int tid = threadIdx.x, lane = tid & 63, wv = tid >> 6;
    if (tid == 0) carry_s = 0;
    __syncthreads();
    for (int base = 0; base < NNODE; base += 4096) {
        int i0 = base + tid * 4;
        int v0 = 0, v1 = 0, v2 = 0, v3 = 0;
        if (i0 + 3 < NNODE) {
            int4 q = *(const int4*)(deg + i0);
            v0 = q.x; v1 = q.y; v2 = q.z; v3 = q.w;
        } else if (i0 < NNODE) {
            v0 = deg[i0];
            if (i0 + 1 < NNODE) v1 = deg[i0 + 1];
            if (i0 + 2 < NNODE) v2 = deg[i0 + 2];
        }
        int tsum = v0 + v1 + v2 + v3;
        int x = tsum;
#pragma unroll
        for (int off = 1; off < 64; off <<= 1) {
            int y = __shfl_up(x, off);
            if (lane >= off) x += y;
        }
        if (lane == 63) wsum[wv] = x;
        __syncthreads();
        if (wv == 0) {
            int s = (lane < 16) ? wsum[lane] : 0;
#pragma unroll
            for (int off = 1; off < 16; off <<= 1) {
                int y = __shfl_up(s, off);
                if (lane >= off) s += y;
            }
            if (lane < 16) wsum[lane] = s;
        }
        __syncthreads();
        int carry = carry_s;
        int woff = wv ? wsum[wv - 1] : 0;
        int e0 = carry + woff + (x - tsum);
        if (i0 < NNODE)     { rowptr[i0] = e0;                cursor[i0] = e0; }
        if (i0 + 1 < NNODE) { int v = e0 + v0;                rowptr[i0+1] = v; cursor[i0+1] = v; }
        if (i0 + 2 < NNODE) { int v = e0 + v0 + v1;           rowptr[i0+2] = v; cursor[i0+2] = v; }
        if (i0 + 3 < NNODE) { int v = e0 + v0 + v1 + v2;      rowptr[i0+3] = v; cursor[i0+3] = v; }
        int total = wsum[15];
        __syncthreads();
        if (tid == 0) carry_s = carry + total;
        __syncthreads();
    }
    if (tid == 0) rowptr[NNODE] = carry_s;
}

__global__ void csr_scatter(const int* __restrict__ ei, const float* __restrict__ attr,
                            int* __restrict__ cursor,
                            int* __restrict__ esrc, float* __restrict__ attr_c) {
    int e = blockIdx.x * 256 + threadIdx.x;
    if (e >= NEDGE) return;
    int s = ei[2 * e], d = ei[2 * e + 1];
    int pos = atomicAdd(&cursor[d], 1);
    esrc[pos] = s;
    attr_c[pos] = attr[e];
}

// ---------------- proj: Ps = h@W1s, Pd = h@W1d (permuted column layout) ----------------
__global__ __launch_bounds__(512, 2)
void proj_kernel(const short* __restrict__ hb,   // [N][128] bf16
                 const short* __restrict__ pW,   // [512][WK]
                 short* __restrict__ Ps,         // [N][256] (permuted cols)
                 short* __restrict__ Pd)         // [N][256] (permuted cols)
{
    __shared__ short A[64][WK];
    const int tid = threadIdx.x;
    const int n0 = blockIdx.x * 64;

    for (int idx = tid; idx < 64 * 16; idx += 512) {
        int nl = idx >> 4, q = idx & 15;
        int gn = min(n0 + nl, NNODE - 1);
        *(bf16x8*)&A[nl][q * 8] = *(const bf16x8*)(hb + (size_t)gn * DIM + q * 8);
    }
    __syncthreads();

    const int lane = tid & 63;
    const int wv = tid >> 6;     // 0..7; wv<4 -> Ps cols, wv>=4 -> Pd cols
    const int lrow = lane & 15;
    const int lkg = lane >> 4;

    f32x4 acc[4][4];
#pragma unroll
    for (int mi = 0; mi < 4; ++mi)
#pragma unroll
        for (int ni = 0; ni < 4; ++ni) acc[mi][ni] = (f32x4){0.f, 0.f, 0.f, 0.f};

    const short* xbase = &A[lrow][lkg * 8];
    const short* wbase = pW + (size_t)(wv * 64 + lrow) * WK + lkg * 8;

#pragma unroll
    for (int kt = 0; kt < 4; ++kt) {
        bf16x8 a[4], b[4];
#pragma unroll
        for (int mi = 0; mi < 4; ++mi)
            a[mi] = *(const bf16x8*)(xbase + mi * 16 * WK + kt * 32);
#pragma unroll
        for (int ni = 0; ni < 4; ++ni)
            b[ni] = *(const bf16x8*)(wbase + ni * 16 * WK + kt * 32);
#pragma unroll
        for (int mi = 0; mi < 4; ++mi)
#pragma unroll
            for (int ni = 0; ni < 4; ++ni)
                acc[mi][ni] = __builtin_amdgcn_mfma_f32_16x16x32_bf16(a[mi], b[ni], acc[mi][ni], 0, 0, 0);
    }

    short* dstP = (wv < 4) ? Ps : Pd;
    const int cb = (wv & 3) * 64;
#pragma unroll
    for (int mi = 0; mi < 4; ++mi)
#pragma unroll
        for (int reg = 0; reg < 4; ++reg) {
            int node = n0 + mi * 16 + lkg * 4 + reg;
            bf16x4 t;
            t[0] = f2bf(acc[mi][0][reg]);
            t[1] = f2bf(acc[mi][1][reg]);
            t[2] = f2bf(acc[mi][2][reg]);
            t[3] = f2bf(acc[mi][3][reg]);
            if (node < NNODE)
                *(bf16x4*)(dstP + (size_t)node * 256 + cb + lrow * 4) = t;
        }
}

// ---------------- fused edge-gate + aggregate: one wave per dst node ----------------
__global__ __launch_bounds__(256)
void edge_agg(const short* __restrict__ Ps, const short* __restrict__ Pd,
              const short* __restrict__ hb,
              const int* __restrict__ esrc, const int* __restrict__ rowptr,
              const float* __restrict__ attr_c,
              const float* __restrict__ w1a_p, const float* __restrict__ b1_p,
              const float* __restrict__ w2_p, const float* __restrict__ b2,
              short* __restrict__ u2)          // aliases Pd: row stride 256, first 128 cols
{
    const int node = (blockIdx.x * 256 + threadIdx.x) >> 6;
    const int lane = threadIdx.x & 63;
    if (node >= NNODE) return;

    const int beg = rowptr[node], end = rowptr[node + 1];
    const int d = end - beg;

    const float4 w1av = ((const float4*)w1a_p)[lane];
    const float4 b1v  = ((const float4*)b1_p)[lane];
    const float4 w2v  = ((const float4*)w2_p)[lane];
    const float b2s = b2[0];

    bf16x4 pd = *(const bf16x4*)(Pd + (size_t)node * 256 + lane * 4);
    const float pb0 = bf2f(pd[0]) + b1v.x;
    const float pb1 = bf2f(pd[1]) + b1v.y;
    const float pb2 = bf2f(pd[2]) + b1v.z;
    const float pb3 = bf2f(pd[3]) + b1v.w;

    int srcl = 0; float al = 0.f;
    if (lane < d) { srcl = esrc[beg + lane]; al = attr_c[beg + lane]; }

    float ax = 0.f, ay = 0.f, den = 0.f;
    const int dm = min(d, 64);

    bf16x4 ps_n = (bf16x4){0,0,0,0};
    unsigned hv_n = 0;
    float a_n = 0.f;
    if (dm > 0) {
        int s0 = __shfl(srcl, 0);
        a_n = __shfl(al, 0);
        ps_n = *(const bf16x4*)(Ps + (size_t)s0 * 256 + lane * 4);
        hv_n = *(const unsigned*)(hb + (size_t)s0 * DIM + lane * 2);
    }
    for (int t = 0; t < dm; ++t) {
        bf16x4 ps = ps_n; unsigned hv = hv_n; float a = a_n;
        if (t + 1 < dm) {
            int s2 = __shfl(srcl, t + 1);
            a_n = __shfl(al, t + 1);
            ps_n = *(const bf16x4*)(Ps + (size_t)s2 * 256 + lane * 4);
            hv_n = *(const unsigned*)(hb + (size_t)s2 * DIM + lane * 2);
        }
        float x0 = bf2f(ps[0]) + pb0 + a * w1av.x;
        float x1 = bf2f(ps[1]) + pb1 + a * w1av.y;
        float x2 = bf2f(ps[2]) + pb2 + a * w1av.z;
        float x3 = bf2f(ps[3]) + pb3 + a * w1av.w;
        float p = gelu_fast(x0) * w2v.x + gelu_fast(x1) * w2v.y +
                  gelu_fast(x2) * w2v.z + gelu_fast(x3) * w2v.w;
        p += __shfl_xor(p, 1);
        p += __shfl_xor(p, 2);
        p += __shfl_xor(p, 4);
        p += __shfl_xor(p, 8);
        p += __shfl_xor(p, 16);
        p += __shfl_xor(p, 32);
        float g = sigmoid_fast(p + b2s);
        ax = fmaf(g, bf2f((short)(hv & 0xFFFFu)), ax);
        ay = fmaf(g, bf2f((short)(hv >> 16)), ay);
        den += g;
    }
    for (int t = 64; t < d; ++t) {       // ultra-rare tail
        int s2 = esrc[beg + t];
        float a = attr_c[beg + t];
        bf16x4 ps = *(const bf16x4*)(Ps + (size_t)s2 * 256 + lane * 4);
        unsigned hv = *(const unsigned*)(hb + (size_t)s2 * DIM + lane * 2);
        float x0 = bf2f(ps[0]) + pb0 + a * w1av.x;
        float x1 = bf2f(ps[1]) + pb1 + a * w1av.y;
        float x2 = bf2f(ps[2]) + pb2 + a * w1av.z;
        float x3 = bf2f(ps[3]) + pb3 + a * w1av.w;
        float p = gelu_fast(x0) * w2v.x + gelu_fast(x1) * w2v.y +
                  gelu_fast(x2) * w2v.z + gelu_fast(x3) * w2v.w;
        p += __shfl_xor(p, 1);
        p += __shfl_xor(p, 2);
        p += __shfl_xor(p, 4);
        p += __shfl_xor(p, 8);
        p += __shfl_xor(p, 16);
        p += __shfl_xor(p, 32);
        float g = sigmoid_fast(p + b2s);
        ax = fmaf(g, bf2f((short)(hv & 0xFFFFu)), ax);
        ay = fmaf(g, bf2f((short)(hv >> 16)), ay);
        den += g;
    }
    float dd = fmaxf(den, 1e-6f);
    float dinv = __builtin_amdgcn_rcpf(dd);
    dinv = dinv * (2.0f - dd * dinv);
    unsigned pk = (((unsigned)(unsigned short)f2bf(ay * dinv)) << 16) |
                  (unsigned)(unsigned short)f2bf(ax * dinv);
    *(unsigned*)(u2 + (size_t)node * 256 + lane * 2) = pk;
}

// ---------------- node MLP: 32 nodes/block, fused GEMM1+gelu+GEMM2+LN ----------------
__global__ __launch_bounds__(256, 4)
void node_mlp(const float* __restrict__ hin,   // f32 residual
              const short* __restrict__ hb,    // bf16
              const short* __restrict__ u2,    // bf16 agg, row stride 256
              const short* __restrict__ W1T,   // [256][WLD]
              const float* __restrict__ b1,
              const short* __restrict__ W2T,   // [128][WLD]
              const float* __restrict__ b2,
              const float* __restrict__ lng, const float* __restrict__ lnb,
              float* __restrict__ hout, short* __restrict__ hb_out)
{
    __shared__ short U[32][WLD];
    __shared__ short G[32][WLD];

    const int tid = threadIdx.x;
    const int n0 = blockIdx.x * 32;   // NNODE % 32 == 0
    const int lane = tid & 63;
    const int wv = tid >> 6;

    for (int idx = tid; idx < 32 * 32; idx += 256) {
        int nl = idx >> 5, q = idx & 31;
        const short* src = (q < 16) ? (hb + (size_t)(n0 + nl) * DIM + q * 8)
                                    : (u2 + (size_t)(n0 + nl) * 256 + (q - 16) * 8);
        *(bf16x8*)&U[nl][q * 8] = *(const bf16x8*)src;
    }
    __syncthreads();

    const int lrow = lane & 15;
    const int lkg = lane >> 4;

    // GEMM1: [32][256] x [256][256]
    {
        const int n0w = wv * 64;
        f32x4 acc1[2][4];
#pragma unroll
        for (int mi = 0; mi < 2; ++mi)
#pragma unroll
            for (int ni = 0; ni < 4; ++ni) acc1[mi][ni] = (f32x4){0.f, 0.f, 0.f, 0.f};

        const short* xbase = &U[lrow][lkg * 8];
        const short* wbase = W1T + (size_t)(n0w + lrow) * WLD + lkg * 8;
#pragma unroll
        for (int kt = 0; kt < 8; ++kt) {
            bf16x8 a[2], b[4];
#pragma unroll
            for (int mi = 0; mi < 2; ++mi)
                a[mi] = *(const bf16x8*)(xbase + mi * 16 * WLD + kt * 32);
#pragma unroll
            for (int ni = 0; ni < 4; ++ni)
                b[ni] = *(const bf16x8*)(wbase + ni * 16 * WLD + kt * 32);
#pragma unroll
            for (int mi = 0; mi < 2; ++mi)
#pragma unroll
                for (int ni = 0; ni < 4; ++ni)
                    acc1[mi][ni] = __builtin_amdgcn_mfma_f32_16x16x32_bf16(a[mi], b[ni], acc1[mi][ni], 0, 0, 0);
        }

        float b1v[4];
#pragma unroll
        for (int ni = 0; ni < 4; ++ni) b1v[ni] = b1[n0w + ni * 16 + lrow];
#pragma unroll
        for (int mi = 0; mi < 2; ++mi)
#pragma unroll
            for (int ni = 0; ni < 4; ++ni)
#pragma unroll
                for (int reg = 0; reg < 4; ++reg) {
                    int row = mi * 16 + lkg * 4 + reg;
                    int col = n0w + ni * 16 + lrow;
                    G[row][col] = f2bf(gelu_erf(acc1[mi][ni][reg] + b1v[ni]));
                }
    }
    __syncthreads();

    // GEMM2: [32][256] x [256][128]
    float* R = (float*)&U[0][0];   // overlay [32][132] f32
    {
        f32x4 acc2[2][2];
#pragma unroll
        for (int mi = 0; mi < 2; ++mi)
#pragma unroll
            for (int ni = 0; ni < 2; ++ni) acc2[mi][ni] = (f32x4){0.f, 0.f, 0.f, 0.f};

        const short* xbase = &G[lrow][lkg * 8];
        const short* wbase = W2T + (size_t)(wv * 32 + lrow) * WLD + lkg * 8;
#pragma unroll
        for (int kt = 0; kt < 8; ++kt) {
            bf16x8 a[2], b[2];
#pragma unroll
            for (int mi = 0; mi < 2; ++mi)
                a[mi] = *(const bf16x8*)(xbase + mi * 16 * WLD + kt * 32);
#pragma unroll
            for (int ni = 0; ni < 2; ++ni)
                b[ni] = *(const bf16x8*)(wbase + ni * 16 * WLD + kt * 32);
#pragma unroll
            for (int mi = 0; mi < 2; ++mi)
#pragma unroll
                for (int ni = 0; ni < 2; ++ni)
                    acc2[mi][ni] = __builtin_amdgcn_mfma_f32_16x16x32_bf16(a[mi], b[ni], acc2[mi][ni], 0, 0, 0);
        }

        float b2v[2];
#pragma unroll
        for (int ni = 0; ni < 2; ++ni) b2v[ni] = b2[wv * 32 + ni * 16 + lrow];
#pragma unroll
        for (int mi = 0; mi < 2; ++mi)
#pragma unroll
            for (int ni = 0; ni < 2; ++ni)
#pragma unroll
                for (int reg = 0; reg < 4; ++reg) {
                    int row = mi * 16 + lkg * 4 + reg;
                    int col = wv * 32 + ni * 16 + lrow;
                    R[row * 132 + col] = acc2[mi][ni][reg] + b2v[ni];
                }
    }
    __syncthreads();

    // residual + LayerNorm; write hout f32 + hb bf16
#pragma unroll
    for (int ii = 0; ii < 8; ++ii) {
        int nl = wv * 8 + ii;
        int gn = n0 + nl;
        float rx = R[nl * 132 + lane * 2 + 0];
        float ry = R[nl * 132 + lane * 2 + 1];
        const float2 hh = *(const float2*)(hin + (size_t)gn * DIM + lane * 2);
        float vx = rx + hh.x, vy = ry + hh.y;
        float s = vx + vy;
#pragma unroll
        for (int off = 32; off > 0; off >>= 1) s += __shfl_xor(s, off);
        float mu = s * (1.0f / 128.0f);
        float dx = vx - mu, dy = vy - mu;
        float q = dx * dx + dy * dy;
#pragma unroll
        for (int off = 32; off > 0; off >>= 1) q += __shfl_xor(q, off);
        float inv = rsqrtf(q * (1.0f / 128.0f) + 1e-5f);
        const float2 gg = *(const float2*)(lng + lane * 2);
        const float2 bb = *(const float2*)(lnb + lane * 2);
        float ox = dx * inv * gg.x + bb.x;
        float oy = dy * inv * gg.y + bb.y;
        *(float2*)(hout + (size_t)gn * DIM + lane * 2) = make_float2(ox, oy);
        unsigned pk = ((unsigned)(unsigned short)f2bf(oy) << 16) |
                      (unsigned)(unsigned short)f2bf(ox);
        *(unsigned*)(hb_out + (size_t)gn * DIM + lane * 2) = pk;
    }
}

extern "C" void kernel_launch(void* const* d_in, const int* in_sizes, int n_in,
                              void* d_out, int out_size, void* d_ws, size_t ws_size,
                              hipStream_t stream) {
    const float* h0   = (const float*)d_in[0];
    const int*   ei   = (const int*)d_in[1];
    const float* attr = (const float*)d_in[2];
    const float* ew1  = (const float*)d_in[3];
    const float* eb1  = (const float*)d_in[4];
    const float* ew2  = (const float*)d_in[5];
    const float* eb2  = (const float*)d_in[6];
    const float* nw1  = (const float*)d_in[7];
    const float* nb1  = (const float*)d_in[8];
    const float* nw2  = (const float*)d_in[9];
    const float* nb2  = (const float*)d_in[10];
    const float* lng  = (const float*)d_in[11];
    const float* lnb  = (const float*)d_in[12];

    float* hout = (float*)d_out;

    char* p = (char*)d_ws;
    int*   rowptr = (int*)p;               p += sizeof(int) * (NNODE + 4);
    int*   cursor = (int*)p;               p += sizeof(int) * (NNODE + 4);
    int*   deg    = (int*)p;               p += sizeof(int) * (NNODE + 4);
    int*   esrc   = (int*)p;               p += sizeof(int) * NEDGE;
    float* attr_c = (float*)p;             p += sizeof(float) * NEDGE;
    short* hb     = (short*)p;             p += sizeof(short) * (size_t)NNODE * DIM;
    short* Ps     = (short*)p;             p += sizeof(short) * (size_t)NNODE * 256;
    short* Pd     = (short*)p;             p += sizeof(short) * (size_t)NNODE * 256;
    short* u2     = Pd;                    // alias: each wave reads only its own Pd row, then writes u2 there
    short* pW     = (short*)p;             p += sizeof(short) * (size_t)NLAYERS * 512 * WK;
    short* nW1T   = (short*)p;             p += sizeof(short) * (size_t)NLAYERS * 256 * WLD;
    short* nW2T   = (short*)p;             p += sizeof(short) * (size_t)NLAYERS * 128 * WLD;
    float* w1a_p  = (float*)p;             p += sizeof(float) * NLAYERS * 256;
    float* b1_p   = (float*)p;             p += sizeof(float) * NLAYERS * 256;
    float* w2_p   = (float*)p;             p += sizeof(float) * NLAYERS * 256;

    hipMemsetAsync(deg, 0, (NNODE + 1) * sizeof(int), stream);
    prep_weights<<<1282, 256, 0, stream>>>(ew1, eb1, ew2, nw1, nw2,
                                           pW, nW1T, nW2T, w1a_p, b1_p, w2_p);
    csr_hist<<<(NEDGE + 255) / 256, 256, 0, stream>>>(ei, deg);
    csr_scan<<<1, 1024, 0, stream>>>(deg, rowptr, cursor);
    csr_scatter<<<(NEDGE + 255) / 256, 256, 0, stream>>>(ei, attr, cursor, esrc, attr_c);
    h2bf<<<(NNODE * DIM / 8 + 255) / 256, 256, 0, stream>>>(h0, hb);

    for (int L = 0; L < NLAYERS; ++L) {
        const float* hin = (L == 0) ? h0 : hout;
        proj_kernel<<<(NNODE + 63) / 64, 512, 0, stream>>>(
            hb, pW + (size_t)L * 512 * WK, Ps, Pd);
        edge_agg<<<(NNODE + 3) / 4, 256, 0, stream>>>(
            Ps, Pd, hb, esrc, rowptr, attr_c,
            w1a_p + (size_t)L * 256, b1_p + (size_t)L * 256,
            w2_p + (size_t)L * 256, eb2 + L, u2);
        node_mlp<<<NNODE / 32, 256, 0, stream>>>(
            hin, hb, u2,
            nW1T + (size_t)L * 256 * WLD, nb1 + (size_t)L * 256,
            nW2T + (size_t)L * 128 * WLD, nb2 + (size_t)L * 128,
            lng + (size_t)L * DIM, lnb + (size_t)L * DIM,
            hout, hb);
    }
}

// Round 6
// 521.019 us; speedup vs baseline: 7.6839x; 1.0165x over previous
//
#include <hip/hip_runtime.h>
#include <math.h>

#define NNODE 100000
#define NEDGE 600000
#define DIM 128
#define HID 256
#define NLAYERS 2

typedef short bf16x8 __attribute__((ext_vector_type(8)));
typedef short bf16x4 __attribute__((ext_vector_type(4)));
typedef float f32x4 __attribute__((ext_vector_type(4)));

#define WK 136    // proj weight LD (k=128 + pad)
#define WLD 264   // node weight / LDS tile LD (k=256 + pad)

__device__ __forceinline__ short f2bf(float x) {
    union { float f; unsigned u; } v; v.f = x;
    unsigned r = v.u + 0x7FFFu + ((v.u >> 16) & 1u);
    return (short)(r >> 16);
}
__device__ __forceinline__ float bf2f(short s) {
    union { unsigned u; float f; } v; v.u = ((unsigned)(unsigned short)s) << 16;
    return v.f;
}
__device__ __forceinline__ float u_lo_f(unsigned u) {
    union { unsigned u; float f; } v; v.u = u << 16; return v.f;
}
__device__ __forceinline__ float u_hi_f(unsigned u) {
    union { unsigned u; float f; } v; v.u = u & 0xFFFF0000u; return v.f;
}
__device__ __forceinline__ float rf_f(float x) {
    return __int_as_float(__builtin_amdgcn_readfirstlane(__float_as_int(x)));
}
// accurate gelu (A&S erf) for node MLP
__device__ __forceinline__ float gelu_erf(float x) {
    float z = x * 0.70710678118654752f;
    float az = fabsf(z);
    float t = __builtin_amdgcn_rcpf(1.0f + 0.3275911f * az);
    float y = t * (0.254829592f + t * (-0.284496736f + t * (1.421413741f +
              t * (-1.453152027f + t * 1.061405429f))));
    float e = __expf(-az * az);
    float er = 1.0f - y * e;
    er = copysignf(er, z);
    return 0.5f * x * (1.0f + er);
}
// fast gelu (sigmoid approx) for edge path: x * sigmoid(1.702 x)
__device__ __forceinline__ float gelu_fast(float x) {
    float e = exp2f(-2.4554673f * x);           // exp(-1.702x)
    return x * __builtin_amdgcn_rcpf(1.0f + e);
}
__device__ __forceinline__ float sigmoid_fast(float z) {
    float e = exp2f(-1.4426950408889634f * z);
    return __builtin_amdgcn_rcpf(1.0f + e);
}

// ---------------- prep: weights -> bf16 transposed (+ permuted edge vectors) + h0->bf16 ----------------
// Hidden-dim storage permutation for Ps/Pd: within each 64-block,
// storage c' = lrow*4 + ni holds semantic col c = ni*16 + lrow.
__global__ void prep_weights(const float* __restrict__ ew1,   // [L][257][256]
                             const float* __restrict__ eb1,   // [L][256]
                             const float* __restrict__ ew2,   // [L][256][1]
                             const float* __restrict__ nw1,   // [L][256][256]
                             const float* __restrict__ nw2,   // [L][256][128]
                             const float* __restrict__ h0,    // [N][128] f32
                             short* __restrict__ pW,          // [L][512][WK]
                             short* __restrict__ nW1T,        // [L][256][WLD]
                             short* __restrict__ nW2T,        // [L][128][WLD]
                             float* __restrict__ w1a_p,       // [L][256] permuted
                             float* __restrict__ b1_p,        // [L][256] permuted
                             float* __restrict__ w2_p,        // [L][256] permuted
                             short* __restrict__ hb)          // [N][128] bf16
{
    int idx = blockIdx.x * 256 + threadIdx.x;
    const int SZ1 = NLAYERS * 512 * 128;
    const int SZ2 = NLAYERS * 256 * 256;
    const int SZ3 = NLAYERS * 128 * 256;
    const int SZ4 = NLAYERS * 256;
    const int SZH = NNODE * DIM / 8;
    if (idx < SZ1) {
        int L = idx / (512 * 128); int rr = idx - L * 512 * 128;
        int r = rr >> 7, k = rr & 127;
        int srow = (r < 256) ? k : 128 + k;
        int scol = (r < 256) ? r : r - 256;
        pW[(size_t)L * 512 * WK + r * WK + k] = f2bf(ew1[(size_t)L * 257 * 256 + srow * 256 + scol]);
        return;
    }
    idx -= SZ1;
    if (idx < SZ2) {
        int L = idx >> 16, r = idx & 65535, n = r >> 8, k = r & 255;
        nW1T[(size_t)L * 256 * WLD + n * WLD + k] = f2bf(nw1[(size_t)L * 256 * 256 + k * 256 + n]);
        return;
    }
    idx -= SZ2;
    if (idx < SZ3) {
        int L = idx >> 15, r = idx & 32767, n = r >> 8, k = r & 255;
        nW2T[(size_t)L * 128 * WLD + n * WLD + k] = f2bf(nw2[(size_t)L * 256 * 128 + k * 128 + n]);
        return;
    }
    idx -= SZ3;
    if (idx < SZ4) {
        int L = idx >> 8, c = idx & 255;
        int cs = (c & ~63) | ((c & 3) * 16 + ((c >> 2) & 15));
        w1a_p[idx] = ew1[(size_t)L * 257 * 256 + 256 * 256 + cs];
        b1_p[idx]  = eb1[(size_t)L * 256 + cs];
        w2_p[idx]  = ew2[(size_t)L * 256 + cs];
        return;
    }
    idx -= SZ4;
    if (idx < SZH) {
        const float4* p = (const float4*)(h0 + (size_t)idx * 8);
        float4 a = p[0], b = p[1];
        bf16x8 t;
        t[0] = f2bf(a.x); t[1] = f2bf(a.y); t[2] = f2bf(a.z); t[3] = f2bf(a.w);
        t[4] = f2bf(b.x); t[5] = f2bf(b.y); t[6] = f2bf(b.z); t[7] = f2bf(b.w);
        *(bf16x8*)(hb + (size_t)idx * 8) = t;
    }
}

// ---------------- CSR build ----------------
__global__ void csr_hist(const int* __restrict__ ei, int* __restrict__ deg) {
    int e = blockIdx.x * 256 + threadIdx.x;
    if (e >= NEDGE) return;
    atomicAdd(&deg[ei[2 * e + 1]], 1);
}

__global__ __launch_bounds__(1024)
void csr_scan(const int* __restrict__ deg, int* __restrict__ rowptr, int* __restrict__ cursor) {
    __shared__ int wsum[16];
    __shared__ int carry_s;
    const int tid = threadIdx.x, lane = tid & 63, wv = tid >> 6;
    if (tid == 0) carry_s = 0;
    __syncthreads();
    for (int base = 0; base < NNODE; base += 4096) {
        int i0 = base + tid * 4;
        int v0 = 0, v1 = 0, v2 = 0, v3 = 0;
        if (i0 + 3 < NNODE) {
            int4 q = *(const int4*)(deg + i0);
            v0 = q.x; v1 = q.y; v2 = q.z; v3 = q.w;
        } else if (i0 < NNODE) {
            v0 = deg[i0];
            if (i0 + 1 < NNODE) v1 = deg[i0 + 1];
            if (i0 + 2 < NNODE) v2 = deg[i0 + 2];
        }
        int tsum = v0 + v1 + v2 + v3;
        int x = tsum;
#pragma unroll
        for (int off = 1; off < 64; off <<= 1) {
            int y = __shfl_up(x, off);
            if (lane >= off) x += y;
        }
        if (lane == 63) wsum[wv] = x;
        __syncthreads();
        if (wv == 0) {
            int s = (lane < 16) ? wsum[lane] : 0;
#pragma unroll
            for (int off = 1; off < 16; off <<= 1) {
                int y = __shfl_up(s, off);
                if (lane >= off) s += y;
            }
            if (lane < 16) wsum[lane] = s;
        }
        __syncthreads();
        int carry = carry_s;
        int woff = wv ? wsum[wv - 1] : 0;
        int e0 = carry + woff + (x - tsum);
        if (i0 < NNODE)     { rowptr[i0] = e0;                cursor[i0] = e0; }
        if (i0 + 1 < NNODE) { int v = e0 + v0;                rowptr[i0+1] = v; cursor[i0+1] = v; }
        if (i0 + 2 < NNODE) { int v = e0 + v0 + v1;           rowptr[i0+2] = v; cursor[i0+2] = v; }
        if (i0 + 3 < NNODE) { int v = e0 + v0 + v1 + v2;      rowptr[i0+3] = v; cursor[i0+3] = v; }
        int total = wsum[15];
        __syncthreads();
        if (tid == 0) carry_s = carry + total;
        __syncthreads();
    }
    if (tid == 0) rowptr[NNODE] = carry_s;
}

__global__ void csr_scatter(const int* __restrict__ ei, const float* __restrict__ attr,
                            int* __restrict__ cursor,
                            int* __restrict__ esrc, float* __restrict__ attr_c) {
    int e = blockIdx.x * 256 + threadIdx.x;
    if (e >= NEDGE) return;
    int s = ei[2 * e], d = ei[2 * e + 1];
    int pos = atomicAdd(&cursor[d], 1);
    esrc[pos] = s;
    attr_c[pos] = attr[e];
}

// ---------------- proj: Ps = h@W1s, Pd = h@W1d (permuted column layout) ----------------
__global__ __launch_bounds__(512, 2)
void proj_kernel(const short* __restrict__ hb,   // [N][128] bf16
                 const short* __restrict__ pW,   // [512][WK]
                 short* __restrict__ Ps,         // [N][256] (permuted cols)
                 short* __restrict__ Pd)         // [N][256] (permuted cols)
{
    __shared__ short A[64][WK];
    const int tid = threadIdx.x;
    const int n0 = blockIdx.x * 64;

    for (int idx = tid; idx < 64 * 16; idx += 512) {
        int nl = idx >> 4, q = idx & 15;
        int gn = min(n0 + nl, NNODE - 1);
        *(bf16x8*)&A[nl][q * 8] = *(const bf16x8*)(hb + (size_t)gn * DIM + q * 8);
    }
    __syncthreads();

    const int lane = tid & 63;
    const int wv = tid >> 6;     // 0..7; wv<4 -> Ps cols, wv>=4 -> Pd cols
    const int lrow = lane & 15;
    const int lkg = lane >> 4;

    f32x4 acc[4][4];
#pragma unroll
    for (int mi = 0; mi < 4; ++mi)
#pragma unroll
        for (int ni = 0; ni < 4; ++ni) acc[mi][ni] = (f32x4){0.f, 0.f, 0.f, 0.f};

    const short* xbase = &A[lrow][lkg * 8];
    const short* wbase = pW + (size_t)(wv * 64 + lrow) * WK + lkg * 8;

#pragma unroll
    for (int kt = 0; kt < 4; ++kt) {
        bf16x8 a[4], b[4];
#pragma unroll
        for (int mi = 0; mi < 4; ++mi)
            a[mi] = *(const bf16x8*)(xbase + mi * 16 * WK + kt * 32);
#pragma unroll
        for (int ni = 0; ni < 4; ++ni)
            b[ni] = *(const bf16x8*)(wbase + ni * 16 * WK + kt * 32);
#pragma unroll
        for (int mi = 0; mi < 4; ++mi)
#pragma unroll
            for (int ni = 0; ni < 4; ++ni)
                acc[mi][ni] = __builtin_amdgcn_mfma_f32_16x16x32_bf16(a[mi], b[ni], acc[mi][ni], 0, 0, 0);
    }

    short* dstP = (wv < 4) ? Ps : Pd;
    const int cb = (wv & 3) * 64;
#pragma unroll
    for (int mi = 0; mi < 4; ++mi)
#pragma unroll
        for (int reg = 0; reg < 4; ++reg) {
            int node = n0 + mi * 16 + lkg * 4 + reg;
            bf16x4 t;
            t[0] = f2bf(acc[mi][0][reg]);
            t[1] = f2bf(acc[mi][1][reg]);
            t[2] = f2bf(acc[mi][2][reg]);
            t[3] = f2bf(acc[mi][3][reg]);
            if (node < NNODE)
                *(bf16x4*)(dstP + (size_t)node * 256 + cb + lrow * 4) = t;
        }
}

// ---------------- fused edge-gate + aggregate: one wave per dst node ----------------
// Scalar-offloaded: per-edge src index / attr / row bases live in SGPRs
// (readfirstlane), so per-iteration addressing is SALU and gathers use
// saddr+fixed-voffset form; no broadcast shuffles for src/attr.
__global__ __launch_bounds__(256)
void edge_agg(const short* __restrict__ Ps, const short* __restrict__ Pd,
              const short* __restrict__ hb,
              const int* __restrict__ esrc, const int* __restrict__ rowptr,
              const float* __restrict__ attr_c,
              const float* __restrict__ w1a_p, const float* __restrict__ b1_p,
              const float* __restrict__ w2_p, const float* __restrict__ b2,
              short* __restrict__ u2)          // aliases Pd: row stride 256, first 128 cols
{
    const int node = (blockIdx.x * 256 + threadIdx.x) >> 6;
    const int lane = threadIdx.x & 63;
    if (node >= NNODE) return;

    const int beg = __builtin_amdgcn_readfirstlane(rowptr[node]);
    const int end = __builtin_amdgcn_readfirstlane(rowptr[node + 1]);
    const int d = end - beg;

    const float4 w1av = ((const float4*)w1a_p)[lane];
    const float4 b1v  = ((const float4*)b1_p)[lane];
    const float4 w2v  = ((const float4*)w2_p)[lane];
    const float b2s = b2[0];

    bf16x4 pd = *(const bf16x4*)(Pd + (size_t)node * 256 + lane * 4);
    const float pb0 = bf2f(pd[0]) + b1v.x;
    const float pb1 = bf2f(pd[1]) + b1v.y;
    const float pb2 = bf2f(pd[2]) + b1v.z;
    const float pb3 = bf2f(pd[3]) + b1v.w;

    const int* ep = esrc + beg;
    const float* ap = attr_c + beg;
    const int pso = lane * 4;   // bf16 elems
    const int hvo = lane * 2;

    float ax = 0.f, ay = 0.f, den = 0.f;

    bf16x4 ps_n = (bf16x4){0, 0, 0, 0};
    unsigned hv_n = 0;
    float a_n = 0.f;
    if (d > 0) {
        int s0 = __builtin_amdgcn_readfirstlane(ep[0]);
        a_n = rf_f(ap[0]);
        ps_n = *(const bf16x4*)(Ps + ((size_t)s0 << 8) + pso);
        hv_n = *(const unsigned*)(hb + ((size_t)s0 << 7) + hvo);
    }
    for (int t = 0; t < d; ++t) {
        bf16x4 ps = ps_n; unsigned hv = hv_n; float a = a_n;
        if (t + 1 < d) {
            int s2 = __builtin_amdgcn_readfirstlane(ep[t + 1]);
            a_n = rf_f(ap[t + 1]);
            ps_n = *(const bf16x4*)(Ps + ((size_t)s2 << 8) + pso);
            hv_n = *(const unsigned*)(hb + ((size_t)s2 << 7) + hvo);
        }
        float x0 = bf2f(ps[0]) + pb0 + a * w1av.x;
        float x1 = bf2f(ps[1]) + pb1 + a * w1av.y;
        float x2 = bf2f(ps[2]) + pb2 + a * w1av.z;
        float x3 = bf2f(ps[3]) + pb3 + a * w1av.w;
        float p = gelu_fast(x0) * w2v.x + gelu_fast(x1) * w2v.y +
                  gelu_fast(x2) * w2v.z + gelu_fast(x3) * w2v.w;
        p += __shfl_xor(p, 1);
        p += __shfl_xor(p, 2);
        p += __shfl_xor(p, 4);
        p += __shfl_xor(p, 8);
        p += __shfl_xor(p, 16);
        p += __shfl_xor(p, 32);
        float g = sigmoid_fast(p + b2s);
        ax = fmaf(g, u_lo_f(hv), ax);
        ay = fmaf(g, u_hi_f(hv), ay);
        den += g;
    }

    float dd = fmaxf(den, 1e-6f);
    float dinv = __builtin_amdgcn_rcpf(dd);
    dinv = dinv * (2.0f - dd * dinv);
    unsigned pk = (((unsigned)(unsigned short)f2bf(ay * dinv)) << 16) |
                  (unsigned)(unsigned short)f2bf(ax * dinv);
    *(unsigned*)(u2 + (size_t)node * 256 + lane * 2) = pk;
}

// ---------------- node MLP: 32 nodes/block, fused GEMM1+gelu+GEMM2+LN ----------------
__global__ __launch_bounds__(256, 4)
void node_mlp(const float* __restrict__ hin,   // f32 residual
              const short* __restrict__ hb,    // bf16
              const short* __restrict__ u2,    // bf16 agg, row stride 256
              const short* __restrict__ W1T,   // [256][WLD]
              const float* __restrict__ b1,
              const short* __restrict__ W2T,   // [128][WLD]
              const float* __restrict__ b2,
              const float* __restrict__ lng, const float* __restrict__ lnb,
              float* __restrict__ hout, short* __restrict__ hb_out)
{
    __shared__ short U[32][WLD];
    __shared__ short G[32][WLD];

    const int tid = threadIdx.x;
    const int n0 = blockIdx.x * 32;   // NNODE % 32 == 0
    const int lane = tid & 63;
    const int wv = tid >> 6;

    for (int idx = tid; idx < 32 * 32; idx += 256) {
        int nl = idx >> 5, q = idx & 31;
        const short* src = (q < 16) ? (hb + (size_t)(n0 + nl) * DIM + q * 8)
                                    : (u2 + (size_t)(n0 + nl) * 256 + (q - 16) * 8);
        *(bf16x8*)&U[nl][q * 8] = *(const bf16x8*)src;
    }
    __syncthreads();

    const int lrow = lane & 15;
    const int lkg = lane >> 4;

    // GEMM1: [32][256] x [256][256]
    {
        const int n0w = wv * 64;
        f32x4 acc1[2][4];
#pragma unroll
        for (int mi = 0; mi < 2; ++mi)
#pragma unroll
            for (int ni = 0; ni < 4; ++ni) acc1[mi][ni] = (f32x4){0.f, 0.f, 0.f, 0.f};

        const short* xbase = &U[lrow][lkg * 8];
        const short* wbase = W1T + (size_t)(n0w + lrow) * WLD + lkg * 8;
#pragma unroll
        for (int kt = 0; kt < 8; ++kt) {
            bf16x8 a[2], b[4];
#pragma unroll
            for (int mi = 0; mi < 2; ++mi)
                a[mi] = *(const bf16x8*)(xbase + mi * 16 * WLD + kt * 32);
#pragma unroll
            for (int ni = 0; ni < 4; ++ni)
                b[ni] = *(const bf16x8*)(wbase + ni * 16 * WLD + kt * 32);
#pragma unroll
            for (int mi = 0; mi < 2; ++mi)
#pragma unroll
                for (int ni = 0; ni < 4; ++ni)
                    acc1[mi][ni] = __builtin_amdgcn_mfma_f32_16x16x32_bf16(a[mi], b[ni], acc1[mi][ni], 0, 0, 0);
        }

        float b1v[4];
#pragma unroll
        for (int ni = 0; ni < 4; ++ni) b1v[ni] = b1[n0w + ni * 16 + lrow];
#pragma unroll
        for (int mi = 0; mi < 2; ++mi)
#pragma unroll
            for (int ni = 0; ni < 4; ++ni)
#pragma unroll
                for (int reg = 0; reg < 4; ++reg) {
                    int row = mi * 16 + lkg * 4 + reg;
                    int col = n0w + ni * 16 + lrow;
                    G[row][col] = f2bf(gelu_erf(acc1[mi][ni][reg] + b1v[ni]));
                }
    }
    __syncthreads();

    // GEMM2: [32][256] x [256][128]
    float* R = (float*)&U[0][0];   // overlay [32][132] f32
    {
        f32x4 acc2[2][2];
#pragma unroll
        for (int mi = 0; mi < 2; ++mi)
#pragma unroll
            for (int ni = 0; ni < 2; ++ni) acc2[mi][ni] = (f32x4){0.f, 0.f, 0.f, 0.f};

        const short* xbase = &G[lrow][lkg * 8];
        const short* wbase = W2T + (size_t)(wv * 32 + lrow) * WLD + lkg * 8;
#pragma unroll
        for (int kt = 0; kt < 8; ++kt) {
            bf16x8 a[2], b[2];
#pragma unroll
            for (int mi = 0; mi < 2; ++mi)
                a[mi] = *(const bf16x8*)(xbase + mi * 16 * WLD + kt * 32);
#pragma unroll
            for (int ni = 0; ni < 2; ++ni)
                b[ni] = *(const bf16x8*)(wbase + ni * 16 * WLD + kt * 32);
#pragma unroll
            for (int mi = 0; mi < 2; ++mi)
#pragma unroll
                for (int ni = 0; ni < 2; ++ni)
                    acc2[mi][ni] = __builtin_amdgcn_mfma_f32_16x16x32_bf16(a[mi], b[ni], acc2[mi][ni], 0, 0, 0);
        }

        float b2v[2];
#pragma unroll
        for (int ni = 0; ni < 2; ++ni) b2v[ni] = b2[wv * 32 + ni * 16 + lrow];
#pragma unroll
        for (int mi = 0; mi < 2; ++mi)
#pragma unroll
            for (int ni = 0; ni < 2; ++ni)
#pragma unroll
                for (int reg = 0; reg < 4; ++reg) {
                    int row = mi * 16 + lkg * 4 + reg;
                    int col = wv * 32 + ni * 16 + lrow;
                    R[row * 132 + col] = acc2[mi][ni][reg] + b2v[ni];
                }
    }
    __syncthreads();

    // residual + LayerNorm; write hout f32 + hb bf16
#pragma unroll
    for (int ii = 0; ii < 8; ++ii) {
        int nl = wv * 8 + ii;
        int gn = n0 + nl;
        float rx = R[nl * 132 + lane * 2 + 0];
        float ry = R[nl * 132 + lane * 2 + 1];
        const float2 hh = *(const float2*)(hin + (size_t)gn * DIM + lane * 2);
        float vx = rx + hh.x, vy = ry + hh.y;
        float s = vx + vy;
#pragma unroll
        for (int off = 32; off > 0; off >>= 1) s += __shfl_xor(s, off);
        float mu = s * (1.0f / 128.0f);
        float dx = vx - mu, dy = vy - mu;
        float q = dx * dx + dy * dy;
#pragma unroll
        for (int off = 32; off > 0; off >>= 1) q += __shfl_xor(q, off);
        float inv = rsqrtf(q * (1.0f / 128.0f) + 1e-5f);
        const float2 gg = *(const float2*)(lng + lane * 2);
        const float2 bb = *(const float2*)(lnb + lane * 2);
        float ox = dx * inv * gg.x + bb.x;
        float oy = dy * inv * gg.y + bb.y;
        *(float2*)(hout + (size_t)gn * DIM + lane * 2) = make_float2(ox, oy);
        unsigned pk = ((unsigned)(unsigned short)f2bf(oy) << 16) |
                      (unsigned)(unsigned short)f2bf(ox);
        *(unsigned*)(hb_out + (size_t)gn * DIM + lane * 2) = pk;
    }
}

extern "C" void kernel_launch(void* const* d_in, const int* in_sizes, int n_in,
                              void* d_out, int out_size, void* d_ws, size_t ws_size,
                              hipStream_t stream) {
    const float* h0   = (const float*)d_in[0];
    const int*   ei   = (const int*)d_in[1];
    const float* attr = (const float*)d_in[2];
    const float* ew1  = (const float*)d_in[3];
    const float* eb1  = (const float*)d_in[4];
    const float* ew2  = (const float*)d_in[5];
    const float* eb2  = (const float*)d_in[6];
    const float* nw1  = (const float*)d_in[7];
    const float* nb1  = (const float*)d_in[8];
    const float* nw2  = (const float*)d_in[9];
    const float* nb2  = (const float*)d_in[10];
    const float* lng  = (const float*)d_in[11];
    const float* lnb  = (const float*)d_in[12];

    float* hout = (float*)d_out;

    char* p = (char*)d_ws;
    int*   rowptr = (int*)p;               p += sizeof(int) * (NNODE + 4);
    int*   cursor = (int*)p;               p += sizeof(int) * (NNODE + 4);
    int*   deg    = (int*)p;               p += sizeof(int) * (NNODE + 4);
    int*   esrc   = (int*)p;               p += sizeof(int) * NEDGE;
    float* attr_c = (float*)p;             p += sizeof(float) * NEDGE;
    short* hb     = (short*)p;             p += sizeof(short) * (size_t)NNODE * DIM;
    short* Ps     = (short*)p;             p += sizeof(short) * (size_t)NNODE * 256;
    short* Pd     = (short*)p;             p += sizeof(short) * (size_t)NNODE * 256;
    short* u2     = Pd;                    // alias: each wave reads only its own Pd row, then writes u2 there
    short* pW     = (short*)p;             p += sizeof(short) * (size_t)NLAYERS * 512 * WK;
    short* nW1T   = (short*)p;             p += sizeof(short) * (size_t)NLAYERS * 256 * WLD;
    short* nW2T   = (short*)p;             p += sizeof(short) * (size_t)NLAYERS * 128 * WLD;
    float* w1a_p  = (float*)p;             p += sizeof(float) * NLAYERS * 256;
    float* b1_p   = (float*)p;             p += sizeof(float) * NLAYERS * 256;
    float* w2_p   = (float*)p;             p += sizeof(float) * NLAYERS * 256;

    const int PREP_TOTAL = NLAYERS * 512 * 128 + NLAYERS * 256 * 256 +
                           NLAYERS * 128 * 256 + NLAYERS * 256 + NNODE * DIM / 8;

    hipMemsetAsync(deg, 0, (NNODE + 1) * sizeof(int), stream);
    prep_weights<<<(PREP_TOTAL + 255) / 256, 256, 0, stream>>>(
        ew1, eb1, ew2, nw1, nw2, h0, pW, nW1T, nW2T, w1a_p, b1_p, w2_p, hb);
    csr_hist<<<(NEDGE + 255) / 256, 256, 0, stream>>>(ei, deg);
    csr_scan<<<1, 1024, 0, stream>>>(deg, rowptr, cursor);
    csr_scatter<<<(NEDGE + 255) / 256, 256, 0, stream>>>(ei, attr, cursor, esrc, attr_c);

    for (int L = 0; L < NLAYERS; ++L) {
        const float* hin = (L == 0) ? h0 : hout;
        proj_kernel<<<(NNODE + 63) / 64, 512, 0, stream>>>(
            hb, pW + (size_t)L * 512 * WK, Ps, Pd);
        edge_agg<<<(NNODE + 3) / 4, 256, 0, stream>>>(
            Ps, Pd, hb, esrc, rowptr, attr_c,
            w1a_p + (size_t)L * 256, b1_p + (size_t)L * 256,
            w2_p + (size_t)L * 256, eb2 + L, u2);
        node_mlp<<<NNODE / 32, 256, 0, stream>>>(
            hin, hb, u2,
            nW1T + (size_t)L * 256 * WLD, nb1 + (size_t)L * 256,
            nW2T + (size_t)L * 128 * WLD, nb2 + (size_t)L * 128,
            lng + (size_t)L * DIM, lnb + (size_t)L * DIM,
            hout, hb);
    }
}